// Round 5
// baseline (2200.180 us; speedup 1.0000x reference)
//
#include <hip/hip_runtime.h>

#define B_  32
#define TX  512
#define TY  1024
#define D_  256
#define H_  2
#define DK  128
#define FN  1024
#define NL  4
#define TXP 520        // TX + 8 halo rows (4 each side) for K=9 convs
#define NEGF (-1e9f)

typedef __attribute__((ext_vector_type(4))) float f32x4;
typedef __attribute__((ext_vector_type(8))) short short8;
typedef __attribute__((ext_vector_type(4))) unsigned short ushort4v;

typedef __attribute__((address_space(3))) unsigned int lds_u32;
typedef __attribute__((address_space(1))) const unsigned int glb_u32;

// ---------- helpers ----------
__device__ __forceinline__ unsigned short f2bf(float x) {
  unsigned int u = __builtin_bit_cast(unsigned int, x);
  u += 0x7fffu + ((u >> 16) & 1u);           // RNE
  return (unsigned short)(u >> 16);
}
__device__ __forceinline__ float bf2f(unsigned short x) {
  unsigned int u = ((unsigned int)x) << 16;
  return __builtin_bit_cast(float, u);
}
__device__ __forceinline__ void store_bf16x4(unsigned short* p, f32x4 v) {
  ushort4v o; o[0]=f2bf(v[0]); o[1]=f2bf(v[1]); o[2]=f2bf(v[2]); o[3]=f2bf(v[3]);
  *(ushort4v*)p = o;
}
__device__ __forceinline__ float wsum(float v) {
#pragma unroll
  for (int i = 1; i < 64; i <<= 1) v += __shfl_xor(v, i, 64);
  return v;
}
__device__ __forceinline__ float wmax(float v) {
#pragma unroll
  for (int i = 1; i < 64; i <<= 1) v = fmaxf(v, __shfl_xor(v, i, 64));
  return v;
}
// async global->LDS, 16B per lane. LDS dest must be wave-uniform base + lane*16.
__device__ __forceinline__ void gl_lds16(const unsigned short* g, unsigned short* l) {
  __builtin_amdgcn_global_load_lds((glb_u32*)g, (lds_u32*)l, 16, 0, 0);
}
__device__ __forceinline__ void gl_lds16f(const float* g, float* l) {
  __builtin_amdgcn_global_load_lds((glb_u32*)g, (lds_u32*)l, 16, 0, 0);
}
// lane i <- lane i-1 (wave_shr:1 DPP); lane 0 gets 0 (bound_ctrl off, old=0)
__device__ __forceinline__ float lane_shr1(float x) {
  int r = __builtin_amdgcn_update_dpp(0, __builtin_bit_cast(int, x), 0x138, 0xF, 0xF, false);
  return __builtin_bit_cast(float, r);
}

// ---------- workspace layout (bytes), total ~169 MB ----------
static const size_t OFF_XB   = 0;
static const size_t SZ_XB    = (size_t)B_*TXP*D_*2;      // bf16 padded activations
static const size_t OFF_HB   = OFF_XB + SZ_XB;
static const size_t SZ_HB    = (size_t)B_*TXP*FN*2;      // bf16 padded conv hidden
static const size_t OFF_QKV  = OFF_HB + SZ_HB;
static const size_t SZ_QKV   = (size_t)B_*TX*768*2;      // q|k|v bf16
static const size_t OFF_S    = OFF_QKV + SZ_QKV;
static const size_t SZ_S     = (size_t)B_*H_*TX*TX*2;    // scores bf16
static const size_t OFF_AO   = OFF_S + SZ_S;
static const size_t SZ_AO    = (size_t)B_*TX*D_*2;       // attn out bf16
static const size_t OFF_T1   = OFF_AO + SZ_AO;
static const size_t SZ_T1    = (size_t)B_*TX*D_*4;       // pre-LN f32
static const size_t OFF_WQKV = OFF_T1 + SZ_T1;
static const size_t SZ_WQKV  = (size_t)NL*768*256*2;
static const size_t OFF_BQKV = OFF_WQKV + SZ_WQKV;
static const size_t SZ_BQKV  = (size_t)NL*768*4;
static const size_t OFF_WO   = OFF_BQKV + SZ_BQKV;
static const size_t SZ_WO    = (size_t)NL*256*256*2;
static const size_t OFF_WT1  = OFF_WO + SZ_WO;
static const size_t SZ_WT1   = (size_t)NL*9*1024*256*2;
static const size_t OFF_WT2  = OFF_WT1 + SZ_WT1;
static const size_t SZ_WT2   = SZ_WT1;
static const size_t OFF_DIRS = OFF_WT2 + SZ_WT2;         // (unused scratch)
static const size_t SZ_DIRS  = (size_t)B_*TY*64;
static const size_t OFF_IDX  = OFF_DIRS + SZ_DIRS;
// phase-local aliases:
//   vT (f32, 64 MB!) at OFF_HB - MAS only. NOTE: 64 MB > SZ_HB (34 MB) — vT
//     deliberately spills across ALL of OFF_QKV and 7.8 MB into OFF_S. Any
//     init of qkvb/S must therefore happen AFTER dp_fused (R2-R4 NaN bug:
//     memset(qkvb) before transpose_mask was overwritten by vT f32 data whose
//     low halves decode as NaN bf16; with skip-blocks those rows were never
//     rewritten, and AV's P*V sum transported the NaN into valid rows).
//   VT (bf16, 8.4 MB) at OFF_T1 - attention-phase V^T; T1 dead between ln read
//     (prev layer) and out-proj write (after AV). NOTE: must NOT overlap HB.

// ---------- weight repacks (f32 inputs -> bf16, B^T layout [K][Cout][Cin]) ----------
__global__ void repack_qkvw(const float* __restrict__ wq, const float* __restrict__ wk,
                            const float* __restrict__ wv, unsigned short* __restrict__ out) {
  int i = blockIdx.x*256 + threadIdx.x;
  if (i >= NL*768*256) return;
  int c = i & 255, j = (i >> 8) % 768, l = i / (768*256);
  const float* src = (j < 256) ? wq : (j < 512) ? wk : wv;
  out[i] = f2bf(src[((size_t)l*256 + c)*256 + (j & 255)]);
}
__global__ void repack_bias(const float* __restrict__ bq, const float* __restrict__ bk,
                            const float* __restrict__ bv, float* __restrict__ out) {
  int i = blockIdx.x*256 + threadIdx.x;
  if (i >= NL*768) return;
  int j = i % 768, l = i / 768;
  const float* src = (j < 256) ? bq : (j < 512) ? bk : bv;
  out[i] = src[l*256 + (j & 255)];
}
__global__ void repack_wo(const float* __restrict__ wo, unsigned short* __restrict__ out) {
  int i = blockIdx.x*256 + threadIdx.x;
  if (i >= NL*256*256) return;
  int c = i & 255, j = (i >> 8) & 255, l = i >> 16;
  out[i] = f2bf(wo[((size_t)l*256 + c)*256 + j]);
}
__global__ void repack_c1(const float* __restrict__ w, unsigned short* __restrict__ out) {
  int i = blockIdx.x*256 + threadIdx.x;
  if (i >= NL*9*1024*256) return;
  int c = i & 255; int rest = i >> 8;
  int f = rest & 1023; int rest2 = rest >> 10;
  int k = rest2 % 9, l = rest2 / 9;
  out[i] = f2bf(w[(((size_t)l*1024 + f)*256 + c)*9 + k]);
}
__global__ void repack_c2(const float* __restrict__ w, unsigned short* __restrict__ out) {
  int i = blockIdx.x*256 + threadIdx.x;
  if (i >= NL*9*256*1024) return;
  int f = i & 1023; int rest = i >> 10;
  int d = rest & 255; int rest2 = rest >> 8;
  int k = rest2 % 9, l = rest2 / 9;
  out[i] = f2bf(w[(((size_t)l*256 + d)*1024 + f)*9 + k]);
}
__global__ void zero_halo(unsigned short* __restrict__ xb, unsigned short* __restrict__ hb) {
  int i = blockIdx.x*256 + threadIdx.x;
  if (i < 65536) {
    int b = i >> 11, r = (i >> 8) & 7, c = i & 255;
    int row = (r < 4) ? r : (512 + r);
    xb[((size_t)b*TXP + row)*256 + c] = 0;
  } else {
    int j = i - 65536;
    if (j < 262144) {
      int b = j >> 13, r = (j >> 10) & 7, c = j & 1023;
      int row = (r < 4) ? r : (512 + r);
      hb[((size_t)b*TXP + row)*1024 + c] = 0;
    }
  }
}

// ---------- embedding ----------
__global__ __launch_bounds__(256) void embed_kernel(const int* __restrict__ tok,
    const float* __restrict__ emb, const float* __restrict__ pos,
    unsigned short* __restrict__ xbo /* pre-offset +4 rows */) {
  int row = blockIdx.x*4 + (threadIdx.x >> 6);
  int t = row & 511, b = row >> 9;
  int lane = threadIdx.x & 63;
  int tk = tok[row];
  f32x4 e = *(const f32x4*)(emb + (size_t)tk*256 + lane*4);
  f32x4 p = *(const f32x4*)(pos + (size_t)t*256 + lane*4);
  f32x4 v;
#pragma unroll
  for (int i = 0; i < 4; i++) v[i] = e[i] + p[i];
  store_bf16x4(xbo + ((size_t)b*TXP + t)*256 + lane*4, v);
}

// ---------- generalized bf16 MFMA GEMM (R1-proven body + block pruning) ------
// out[t][f] = sum_k sum_c A[b,h][t+k][c] * W[b,h][k*Cout + f][c]   (+ epilogue)
// z decodes to (b,h) when H==2. maskmode=1: v = acc*scale, NEG where f>=sl[b].
//  - tskip: early return for t-blocks that only produce pad rows.
//  - maskmode && f0>=sl[b]: skip the whole K-loop; epilogue fills NEG.
__global__ __launch_bounds__(256) void gemm_mfma(
    const unsigned short* __restrict__ A, long long AbO, long long AhO, int Astr,
    const unsigned short* __restrict__ W, long long WbO, long long WhO, int Wstr,
    const float* __restrict__ bias,
    float* __restrict__ O32, long long O32bO, int O32str,
    unsigned short* __restrict__ O16, long long O16bO, long long O16hO, int O16str,
    int Cin, int Cout, int ks, int relu, int H,
    const int* __restrict__ sl, float scale, int maskmode,
    const int* __restrict__ tskip, int tmargin) {
  __shared__ unsigned short As[128*32];   // [row][32ch] unpadded, 8 KB
  __shared__ unsigned short Ws[128*32];
  const int tid = threadIdx.x;
  int b, h;
  if (H == 2) { b = blockIdx.z >> 1; h = blockIdx.z & 1; }
  else        { b = blockIdx.z;      h = 0; }
  const int t0 = blockIdx.x * 128;
  const int f0 = blockIdx.y * 128;
  if (tskip && t0 >= tskip[b] + tmargin) return;   // block-uniform, pre-barrier
  const int slb = maskmode ? sl[b] : 0;
  const unsigned short* Ab = A + (size_t)b * AbO + (size_t)h * AhO;
  const unsigned short* Wb = W + (size_t)b * WbO + (size_t)h * WhO;
  const int lane = tid & 63, w = tid >> 6;
  const int wt = (w & 1) << 6, wf = (w >> 1) << 6;
  const int lr = lane & 15, lh = lane >> 4;
  const int r0 = tid >> 2, cg = (tid & 3) << 3;
  f32x4 zed = {0.f, 0.f, 0.f, 0.f};
  f32x4 acc[4][4];
#pragma unroll
  for (int i = 0; i < 4; i++)
#pragma unroll
    for (int j = 0; j < 4; j++) acc[i][j] = zed;

  const bool skipK = maskmode && (f0 >= slb);   // block-uniform
  if (!skipK) {
    for (int k = 0; k < ks; ++k) {
      const unsigned short* AkB = Ab + (size_t)(t0 + k) * Astr;
      const unsigned short* WkB = Wb + ((size_t)k * Cout + f0) * Wstr;
      for (int c0 = 0; c0 < Cin; c0 += 32) {
        __syncthreads();
        gl_lds16(AkB + (size_t)r0 * Astr + (c0 + cg),        As + (size_t)tid * 8);
        gl_lds16(AkB + (size_t)(r0 + 64) * Astr + (c0 + cg), As + (size_t)(tid + 256) * 8);
        gl_lds16(WkB + (size_t)r0 * Wstr + (c0 + cg),        Ws + (size_t)tid * 8);
        gl_lds16(WkB + (size_t)(r0 + 64) * Wstr + (c0 + cg), Ws + (size_t)(tid + 256) * 8);
        __syncthreads();
        short8 af[4], bfv[4];
#pragma unroll
        for (int mt = 0; mt < 4; mt++) af[mt]  = *(const short8*)&As[(wt + mt*16 + lr)*32 + lh*8];
#pragma unroll
        for (int nt = 0; nt < 4; nt++) bfv[nt] = *(const short8*)&Ws[(wf + nt*16 + lr)*32 + lh*8];
#pragma unroll
        for (int mt = 0; mt < 4; mt++)
#pragma unroll
          for (int nt = 0; nt < 4; nt++)
            acc[mt][nt] = __builtin_amdgcn_mfma_f32_16x16x32_bf16(af[mt], bfv[nt], acc[mt][nt], 0, 0, 0);
      }
    }
  }
  // epilogue: D row t = (lane>>4)*4+r, col f = lane&15
#pragma unroll
  for (int mt = 0; mt < 4; mt++) {
    int trow = t0 + wt + mt*16 + lh*4;
#pragma unroll
    for (int nt = 0; nt < 4; nt++) {
      int f = f0 + wf + nt*16 + lr;
      float bb = (!maskmode && bias) ? bias[f] : 0.f;
#pragma unroll
      for (int r = 0; r < 4; r++) {
        float v;
        if (maskmode) {
          v = acc[mt][nt][r] * scale;
          if (f >= slb) v = NEGF;
        } else {
          v = acc[mt][nt][r] + bb;
          if (relu) v = fmaxf(v, 0.f);
        }
        if (O32) O32[(size_t)b*O32bO + (size_t)(trow + r)*O32str + f] = v;
        if (O16) O16[(size_t)b*O16bO + (size_t)h*O16hO + (size_t)(trow + r)*O16str + f] = f2bf(v);
      }
    }
  }
}

// ---------- V transpose: VT[bh][d][t] <- qkv V section; zero t >= sl[b] ------
// Zeroing makes the V path NaN-proof regardless of qkvb's stale-row content
// (P*V sums over t, so one non-finite V row would poison every valid output).
__global__ __launch_bounds__(256) void vtrans_kernel(const unsigned short* __restrict__ qkv,
    const int* __restrict__ sl, unsigned short* __restrict__ VT) {
  const int z = blockIdx.z, b = z >> 1, h = z & 1;
  const int t0 = blockIdx.x << 5, d0 = blockIdx.y << 5;
  __shared__ unsigned short tile[32][33];
  const int tx = threadIdx.x, ty = threadIdx.y;
  const int slb = sl[b];
  const unsigned short* src = qkv + (size_t)b*TX*768 + 512 + h*DK;
#pragma unroll
  for (int i = 0; i < 4; i++)
    tile[ty + i*8][tx] = src[(size_t)(t0 + ty + i*8)*768 + d0 + tx];
  __syncthreads();
#pragma unroll
  for (int i = 0; i < 4; i++) {
    unsigned short v = (t0 + tx < slb) ? tile[tx][ty + i*8] : (unsigned short)0;
    VT[((size_t)z*DK + d0 + ty + i*8)*512 + t0 + tx] = v;
  }
}

// ---------- softmax over bf16 score rows ----------
__global__ __launch_bounds__(256) void softmax_kernel(unsigned short* __restrict__ S) {
  const int row = blockIdx.x*4 + (threadIdx.x >> 6);
  const int lane = threadIdx.x & 63;
  unsigned short* p = S + (size_t)row*512 + lane*8;
  short8 raw = *(const short8*)p;
  float a[8];
#pragma unroll
  for (int i = 0; i < 8; i++) a[i] = bf2f((unsigned short)raw[i]);
  float m = a[0];
#pragma unroll
  for (int i = 1; i < 8; i++) m = fmaxf(m, a[i]);
  m = wmax(m);
  float s = 0.f;
#pragma unroll
  for (int i = 0; i < 8; i++) { a[i] = __expf(a[i]-m); s += a[i]; }
  s = wsum(s);
  float inv = 1.f / s;
  short8 o;
#pragma unroll
  for (int i = 0; i < 8; i++) o[i] = (short)f2bf(a[i] * inv);
  *(short8*)p = o;
}

// ---------- residual(bf16) + layernorm + pad-mask; rewrites bf16 padded xb ----------
__global__ __launch_bounds__(256) void ln_kernel(const float* __restrict__ tin,
    const float* __restrict__ g, const float* __restrict__ bt, const int* __restrict__ sl,
    unsigned short* __restrict__ xbo /* pre-offset +4 rows */) {
  const int row = blockIdx.x*4 + (threadIdx.x >> 6);
  const int b = row >> 9, t = row & 511;
  const int lane = threadIdx.x & 63;
  unsigned short* xp = xbo + ((size_t)b*TXP + t)*256 + lane*4;
  f32x4 tv = *(const f32x4*)(tin + (size_t)row*256 + lane*4);
  ushort4v rv4 = *(const ushort4v*)xp;
  f32x4 s; float su = 0.f, sq = 0.f;
#pragma unroll
  for (int i = 0; i < 4; i++) {
    s[i] = tv[i] + bf2f(rv4[i]);
    su += s[i]; sq += s[i]*s[i];
  }
  su = wsum(su); sq = wsum(sq);
  float mean = su * (1.f/256.f);
  float var = fmaxf(sq * (1.f/256.f) - mean*mean, 0.f);
  float rs = rsqrtf(var + 1e-5f);
  f32x4 gg = *(const f32x4*)(g + lane*4);
  f32x4 bb = *(const f32x4*)(bt + lane*4);
  bool padr = (t >= sl[b]);
  f32x4 y;
#pragma unroll
  for (int i = 0; i < 4; i++) {
    float yy = (s[i]-mean)*rs*gg[i] + bb[i];
    y[i] = padr ? 0.f : yy;
  }
  store_bf16x4(xp, y);
}

// ---------- MAS: masked transpose of value ----------
__global__ __launch_bounds__(256) void transpose_mask(const float* __restrict__ value,
    const int* __restrict__ sl, const int* __restrict__ ml, float* __restrict__ vT) {
  const int b = blockIdx.z;
  const int x0 = blockIdx.y << 5, y0 = blockIdx.x << 5;
  __shared__ float tile[32][33];
  const int tx = threadIdx.x, ty = threadIdx.y;
  const int slb = sl[b], mlb = ml[b];
#pragma unroll
  for (int i = 0; i < 4; i++) {
    int x = x0 + ty + i*8, y = y0 + tx;
    float v = value[((size_t)b*TX + x)*TY + y];
    tile[ty + i*8][tx] = (x < slb && y < mlb) ? v : 0.f;
  }
  __syncthreads();
#pragma unroll
  for (int i = 0; i < 4; i++) {
    int y = y0 + ty + i*8, x = x0 + tx;
    vT[((size_t)b*TY + y)*TX + x] = tile[tx][ty + i*8];
  }
}

// ---------- fused MAS DP (forward + backward), one wave per batch ----------
template<bool RAMP>
__device__ __forceinline__ void dp_comp8(
    int jb, const float* valbuf, unsigned long long* dll,
    float v[8], int lane, int xbase, unsigned int vmask, unsigned int fmask,
    bool lane0) {
  unsigned int w0 = 0, w1 = 0;
#pragma unroll
  for (int u = 0; u < 8; ++u) {
    const int j = jb*8 + u;
    f32x4 a0 = *(const f32x4*)(valbuf + u*512 + lane*8);
    f32x4 a1 = *(const f32x4*)(valbuf + u*512 + lane*8 + 4);
    float vp = lane_shr1(v[7]);          // old v[7] of lane-1
    if (lane0) vp = NEGF;
    unsigned int ge = 0;
#pragma unroll
    for (int i = 7; i >= 1; --i) {       // descending: v[i-1] still old
      unsigned int g = (v[i] >= v[i-1]) ? 1u : 0u;
      ge = (ge << 1) | g;
      float nv = fmaxf(v[i], v[i-1]) + ((i < 4) ? a0[i] : a1[i-4]);
      if (RAMP) v[i] = (xbase + i <= j) ? nv : NEGF;
      else      v[i] = nv;
    }
    {
      unsigned int g = (v[0] >= vp) ? 1u : 0u;
      ge = (ge << 1) | g;
      float nv = fmaxf(v[0], vp) + a0[0];
      if (RAMP) v[0] = (xbase <= j) ? nv : NEGF;
      else      v[0] = nv;
    }
    unsigned int byt = (ge & vmask) | fmask;   // force-1 where x >= slb
    if (u < 4) w0 |= byt << (8*u); else w1 |= byt << (8*(u-4));
  }
  dll[jb*64 + lane] = ((unsigned long long)w1 << 32) | w0;
}

__global__ __launch_bounds__(64, 1) void dp_fused(const float* __restrict__ vT,
    const int* __restrict__ sl, const int* __restrict__ ml,
    int* __restrict__ idxout) {
  __shared__ float sval[3*4096];              // 3 x (8 j x 512 x) f32 = 48 KB
  __shared__ unsigned long long dll[TY*8];    // direction bitmap, 64 KB
  unsigned char* dld = (unsigned char*)dll;
  const int b = blockIdx.x, lane = threadIdx.x;
  const int slb = sl[b], mlb = ml[b];
  const float* vb = vT + (size_t)b*TY*TX;
  const int xbase = lane*8;
  const bool lane0 = (lane == 0);
  unsigned int vmaskv = 0;
#pragma unroll
  for (int i = 0; i < 8; ++i) if (xbase + i < slb) vmaskv |= (1u << i);
  const unsigned int fmaskv = (~vmaskv) & 0xffu;
  float v[8];
#pragma unroll
  for (int i = 0; i < 8; ++i) v[i] = 0.f;
  const int jbEnd = (mlb + 7) >> 3;           // in [64,128]

  auto stage = [&](int jb, float* buf) {      // 16 async loads, 16B/lane
    const float* src = vb + (size_t)jb*8*TX;
#pragma unroll
    for (int u = 0; u < 8; ++u) {
      gl_lds16f(src + u*TX + lane*4,       buf + u*512);
      gl_lds16f(src + u*TX + 256 + lane*4, buf + u*512 + 256);
    }
  };
  stage(0, sval);
  stage(1, sval + 4096);
  stage(2, sval + 8192);
  int buf = 0;
  int jb = 0;
  for (; jb < 64; ++jb) {
    if (jb + 2 < jbEnd)      asm volatile("s_waitcnt vmcnt(32)" ::: "memory");
    else if (jb + 1 < jbEnd) asm volatile("s_waitcnt vmcnt(16)" ::: "memory");
    else                     asm volatile("s_waitcnt vmcnt(0)"  ::: "memory");
    float* vbuf = sval + buf*4096;
    dp_comp8<true>(jb, vbuf, dll, v, lane, xbase, vmaskv, fmaskv, lane0);
    __builtin_amdgcn_sched_barrier(0);
    if (jb + 3 < jbEnd) stage(jb + 3, vbuf);
    buf = (buf == 2) ? 0 : buf + 1;
  }
  for (; jb < jbEnd; ++jb) {
    if (jb + 2 < jbEnd)      asm volatile("s_waitcnt vmcnt(32)" ::: "memory");
    else if (jb + 1 < jbEnd) asm volatile("s_waitcnt vmcnt(16)" ::: "memory");
    else                     asm volatile("s_waitcnt vmcnt(0)"  ::: "memory");
    float* vbuf = sval + buf*4096;
    dp_comp8<false>(jb, vbuf, dll, v, lane, xbase, vmaskv, fmaskv, lane0);
    __builtin_amdgcn_sched_barrier(0);
    if (jb + 3 < jbEnd) stage(jb + 3, vbuf);
    buf = (buf == 2) ? 0 : buf + 1;
  }
  for (int jj = mlb + lane; jj < TY; jj += 64) idxout[b*TY + jj] = -1;
  if (lane0) {
    int* ob = idxout + b*TY;
    int idx = slb - 1;
    int j = mlb - 1;
    while (j >= 6) {
      int o0 = idx >> 3;
      int o1 = (o0 > 0) ? (o0 - 1) : 0;
      unsigned int bc[7], ba[7];
#pragma unroll
      for (int s = 0; s < 7; ++s) {       // 14 independent ds_read_u8
        int r = j - s;
        int rbase = ((r >> 3) << 9) + (r & 7);
        bc[s] = dld[rbase + o0*8];
        ba[s] = dld[rbase + o1*8];
      }
#pragma unroll
      for (int s = 0; s < 7; ++s) {
        ob[j - s] = idx;
        unsigned int byt = ((idx >> 3) == o0) ? bc[s] : ba[s];
        idx += (int)((byt >> (idx & 7)) & 1u) - 1;
      }
      j -= 7;
    }
    while (j >= 0) {
      ob[j] = idx;
      unsigned int byt = dld[((j >> 3) << 9) + (j & 7) + (idx >> 3)*8];
      idx += (int)((byt >> (idx & 7)) & 1u) - 1;
      --j;
    }
  }
}

// ---------- final gather (bf16 activations -> f32 out) ----------
__global__ __launch_bounds__(256) void gather_kernel(const unsigned short* __restrict__ xbo,
    const int* __restrict__ idxout, float* __restrict__ out) {
  const int row = blockIdx.x*4 + (threadIdx.x >> 6);
  const int lane = threadIdx.x & 63;
  const int b = row >> 10;
  const int idx = idxout[row];
  f32x4 v;
  if (idx >= 0) {
    ushort4v r = *(const ushort4v*)(xbo + ((size_t)b*TXP + idx)*256 + lane*4);
#pragma unroll
    for (int i = 0; i < 4; i++) v[i] = bf2f(r[i]);
  } else { v[0]=0.f; v[1]=0.f; v[2]=0.f; v[3]=0.f; }
  *(f32x4*)(out + (size_t)row*256 + lane*4) = v;
}

// ---------- launch ----------
extern "C" void kernel_launch(void* const* d_in, const int* in_sizes, int n_in,
                              void* d_out, int out_size, void* d_ws, size_t ws_size,
                              hipStream_t stream) {
  const int*   tokens = (const int*)d_in[0];
  const int*   sl     = (const int*)d_in[1];
  const int*   ml     = (const int*)d_in[2];
  const float* value  = (const float*)d_in[3];
  const float* emb    = (const float*)d_in[4];
  const float* pos    = (const float*)d_in[5];
  const float* wq     = (const float*)d_in[6];
  const float* bq     = (const float*)d_in[7];
  const float* wk     = (const float*)d_in[8];
  const float* bk     = (const float*)d_in[9];
  const float* wv     = (const float*)d_in[10];
  const float* bv     = (const float*)d_in[11];
  const float* wo     = (const float*)d_in[12];
  const float* bo     = (const float*)d_in[13];
  const float* ln1g   = (const float*)d_in[14];
  const float* ln1bb  = (const float*)d_in[15];
  const float* c1w    = (const float*)d_in[16];
  const float* c1b    = (const float*)d_in[17];
  const float* c2w    = (const float*)d_in[18];
  const float* c2b    = (const float*)d_in[19];
  const float* ln2g   = (const float*)d_in[20];
  const float* ln2bb  = (const float*)d_in[21];

  char* w8 = (char*)d_ws;
  unsigned short* xb     = (unsigned short*)(w8 + OFF_XB);
  unsigned short* hb     = (unsigned short*)(w8 + OFF_HB);
  unsigned short* qkvb   = (unsigned short*)(w8 + OFF_QKV);
  unsigned short* S      = (unsigned short*)(w8 + OFF_S);
  float*          vT     = (float*)(w8 + OFF_HB);            // MAS-phase alias
  unsigned short* VT     = (unsigned short*)(w8 + OFF_T1);   // attention-phase alias
  unsigned short* ao     = (unsigned short*)(w8 + OFF_AO);
  float*          T1     = (float*)(w8 + OFF_T1);
  unsigned short* wqkv_r = (unsigned short*)(w8 + OFF_WQKV);
  float*          bqkv   = (float*)(w8 + OFF_BQKV);
  unsigned short* wo_r   = (unsigned short*)(w8 + OFF_WO);
  unsigned short* wt1r   = (unsigned short*)(w8 + OFF_WT1);
  unsigned short* wt2r   = (unsigned short*)(w8 + OFF_WT2);
  int*            idxout = (int*)(w8 + OFF_IDX);
  float*          out    = (float*)d_out;

  const float scale = 0.08838834764831843f;  // 1/sqrt(128)

  // weight repack
  repack_qkvw<<<(NL*768*256 + 255)/256, 256, 0, stream>>>(wq, wk, wv, wqkv_r);
  repack_bias<<<(NL*768 + 255)/256, 256, 0, stream>>>(bq, bk, bv, bqkv);
  repack_wo<<<(NL*256*256 + 255)/256, 256, 0, stream>>>(wo, wo_r);
  repack_c1<<<(NL*9*1024*256 + 255)/256, 256, 0, stream>>>(c1w, wt1r);
  repack_c2<<<(NL*9*256*1024 + 255)/256, 256, 0, stream>>>(c2w, wt2r);

  // monotonic alignment search first (vT aliases HB+QKV+part of S!)
  transpose_mask<<<dim3(32, 16, 32), dim3(32, 8), 0, stream>>>(value, sl, ml, vT);
  dp_fused<<<32, 64, 0, stream>>>(vT, sl, ml, idxout);

  // qkvb must be finite everywhere (skip-blocks leave rows >= sl unwritten;
  // K-side stale NaN is confined to NEG-overwritten columns, but keep zeros
  // for determinism). MUST be issued AFTER dp_fused: vT covers this region.
  hipMemsetAsync(qkvb, 0, SZ_QKV, stream);

  // halo zero + embedding
  zero_halo<<<(327680 + 255)/256, 256, 0, stream>>>(xb, hb);
  embed_kernel<<<4096, 256, 0, stream>>>(tokens, emb, pos, xb + 4*256);

  // encoder layers
  for (int l = 0; l < NL; l++) {
    // QKV projection: [B] x: 512x256 @ 256x768 -> qkvb bf16
    gemm_mfma<<<dim3(4, 6, 32), 256, 0, stream>>>(
        xb + 4*256, (long long)TXP*256, 0, 256,
        wqkv_r + (size_t)l*768*256, 0, 0, 256,
        bqkv + l*768,
        nullptr, 0, 0,
        qkvb, (long long)TX*768, 0, 768,
        256, 768, 1, 0, 1, nullptr, 0.f, 0, sl, 0);
    // scores: per (b,h): Q[512x128] @ K^T -> S bf16, scale + key mask
    gemm_mfma<<<dim3(4, 4, 64), 256, 0, stream>>>(
        qkvb, (long long)TX*768, 128, 768,
        qkvb + 256, (long long)TX*768, 128, 768,
        nullptr,
        nullptr, 0, 0,
        S, (long long)2*512*512, (long long)512*512, 512,
        128, 512, 1, 0, 2, sl, scale, 1, sl, 0);
    softmax_kernel<<<8192, 256, 0, stream>>>(S);
    vtrans_kernel<<<dim3(16, 4, 64), dim3(32, 8), 0, stream>>>(qkvb, sl, VT);
    // AV: per (b,h): P[512x512] @ V[512x128] (VT rows are d) -> ao bf16
    gemm_mfma<<<dim3(4, 1, 64), 256, 0, stream>>>(
        S, (long long)2*512*512, (long long)512*512, 512,
        VT, (long long)2*DK*512, (long long)DK*512, 512,
        nullptr,
        nullptr, 0, 0,
        ao, (long long)TX*256, 128, 256,
        512, 128, 1, 0, 2, nullptr, 0.f, 0, sl, 0);
    // out-proj -> T1 f32 (after AV: T1/VT alias hand-off)
    gemm_mfma<<<dim3(4, 2, 32), 256, 0, stream>>>(
        ao, (long long)TX*256, 0, 256,
        wo_r + (size_t)l*256*256, 0, 0, 256,
        bo + l*256,
        T1, (long long)TX*256, 256,
        nullptr, 0, 0, 0,
        256, 256, 1, 0, 1, nullptr, 0.f, 0, sl, 0);
    ln_kernel<<<4096, 256, 0, stream>>>(T1, ln1g + l*256, ln1bb + l*256, sl, xb + 4*256);
    // conv1 (K=9) -> hb bf16 (relu); outputs needed for rows < sl+4
    gemm_mfma<<<dim3(4, 8, 32), 256, 0, stream>>>(
        xb, (long long)TXP*256, 0, 256,
        wt1r + (size_t)l*9*1024*256, 0, 0, 256,
        c1b + l*1024,
        nullptr, 0, 0,
        hb + 4*1024, (long long)TXP*1024, 0, 1024,
        256, 1024, 9, 1, 1, nullptr, 0.f, 0, sl, 4);
    // conv2 (K=9) -> T1 f32
    gemm_mfma<<<dim3(4, 2, 32), 256, 0, stream>>>(
        hb, (long long)TXP*1024, 0, 1024,
        wt2r + (size_t)l*9*256*1024, 0, 0, 1024,
        c2b + l*256,
        T1, (long long)TX*256, 256,
        nullptr, 0, 0, 0,
        1024, 256, 9, 0, 1, nullptr, 0.f, 0, sl, 0);
    ln_kernel<<<4096, 256, 0, stream>>>(T1, ln2g + l*256, ln2bb + l*256, sl, xb + 4*256);
  }

  // expand via alignment path
  gather_kernel<<<8192, 256, 0, stream>>>(xb + 4*256, idxout, out);
  (void)in_sizes; (void)n_in; (void)out_size; (void)ws_size;
}

// Round 6
// 2028.485 us; speedup vs baseline: 1.0846x; 1.0846x over previous
//
#include <hip/hip_runtime.h>

#define B_  32
#define TX  512
#define TY  1024
#define D_  256
#define H_  2
#define DK  128
#define FN  1024
#define NL  4
#define TXP 520        // TX + 8 halo rows (4 each side) for K=9 convs
#define NEGF (-1e9f)

typedef __attribute__((ext_vector_type(4))) float f32x4;
typedef __attribute__((ext_vector_type(8))) short short8;
typedef __attribute__((ext_vector_type(4))) unsigned short ushort4v;

typedef __attribute__((address_space(3))) unsigned int lds_u32;
typedef __attribute__((address_space(1))) const unsigned int glb_u32;

// ---------- helpers ----------
__device__ __forceinline__ unsigned short f2bf(float x) {
  unsigned int u = __builtin_bit_cast(unsigned int, x);
  u += 0x7fffu + ((u >> 16) & 1u);           // RNE
  return (unsigned short)(u >> 16);
}
__device__ __forceinline__ float bf2f(unsigned short x) {
  unsigned int u = ((unsigned int)x) << 16;
  return __builtin_bit_cast(float, u);
}
__device__ __forceinline__ void store_bf16x4(unsigned short* p, f32x4 v) {
  ushort4v o; o[0]=f2bf(v[0]); o[1]=f2bf(v[1]); o[2]=f2bf(v[2]); o[3]=f2bf(v[3]);
  *(ushort4v*)p = o;
}
__device__ __forceinline__ float wsum(float v) {
#pragma unroll
  for (int i = 1; i < 64; i <<= 1) v += __shfl_xor(v, i, 64);
  return v;
}
__device__ __forceinline__ float wmax(float v) {
#pragma unroll
  for (int i = 1; i < 64; i <<= 1) v = fmaxf(v, __shfl_xor(v, i, 64));
  return v;
}
// async global->LDS, 16B per lane. LDS dest is wave-uniform base + lane*16.
__device__ __forceinline__ void gl_lds16(const unsigned short* g, unsigned short* l) {
  __builtin_amdgcn_global_load_lds((glb_u32*)g, (lds_u32*)l, 16, 0, 0);
}
__device__ __forceinline__ void gl_lds16f(const float* g, float* l) {
  __builtin_amdgcn_global_load_lds((glb_u32*)g, (lds_u32*)l, 16, 0, 0);
}
// lane i <- lane i-1 (wave_shr:1 DPP); lane 0 gets 0 (bound_ctrl off, old=0)
__device__ __forceinline__ float lane_shr1(float x) {
  int r = __builtin_amdgcn_update_dpp(0, __builtin_bit_cast(int, x), 0x138, 0xF, 0xF, false);
  return __builtin_bit_cast(float, r);
}

// ---------- workspace layout (bytes), total ~169 MB ----------
static const size_t OFF_XB   = 0;
static const size_t SZ_XB    = (size_t)B_*TXP*D_*2;      // bf16 padded activations
static const size_t OFF_HB   = OFF_XB + SZ_XB;
static const size_t SZ_HB    = (size_t)B_*TXP*FN*2;      // bf16 padded conv hidden
static const size_t OFF_QKV  = OFF_HB + SZ_HB;
static const size_t SZ_QKV   = (size_t)B_*TX*768*2;      // q|k|v bf16
static const size_t OFF_S    = OFF_QKV + SZ_QKV;
static const size_t SZ_S     = (size_t)B_*H_*TX*TX*2;    // scores bf16
static const size_t OFF_AO   = OFF_S + SZ_S;
static const size_t SZ_AO    = (size_t)B_*TX*D_*2;       // attn out bf16
static const size_t OFF_T1   = OFF_AO + SZ_AO;
static const size_t SZ_T1    = (size_t)B_*TX*D_*4;       // pre-LN f32
static const size_t OFF_WQKV = OFF_T1 + SZ_T1;
static const size_t SZ_WQKV  = (size_t)NL*768*256*2;
static const size_t OFF_BQKV = OFF_WQKV + SZ_WQKV;
static const size_t SZ_BQKV  = (size_t)NL*768*4;
static const size_t OFF_WO   = OFF_BQKV + SZ_BQKV;
static const size_t SZ_WO    = (size_t)NL*256*256*2;
static const size_t OFF_WT1  = OFF_WO + SZ_WO;
static const size_t SZ_WT1   = (size_t)NL*9*1024*256*2;
static const size_t OFF_WT2  = OFF_WT1 + SZ_WT1;
static const size_t SZ_WT2   = SZ_WT1;
static const size_t OFF_DIRS = OFF_WT2 + SZ_WT2;         // (unused scratch)
static const size_t SZ_DIRS  = (size_t)B_*TY*64;
static const size_t OFF_IDX  = OFF_DIRS + SZ_DIRS;
// phase-local aliases:
//   vT (f32, 64 MB!) at OFF_HB - MAS only. NOTE: 64 MB > SZ_HB (34 MB) — vT
//     deliberately spills across ALL of OFF_QKV and 7.8 MB into OFF_S. Any
//     init of qkvb/S must happen AFTER dp_fused (R2-R4 NaN bug: memset(qkvb)
//     before transpose_mask was overwritten by vT f32 data whose low halves
//     decode as NaN bf16; AV's P*V sum transported the NaN into valid rows).
//   VT (bf16, 8.4 MB) at OFF_T1 - attention-phase V^T; T1 dead between ln read
//     (prev layer) and out-proj write (after AV). NOTE: must NOT overlap HB.

// ---------- weight repacks (f32 inputs -> bf16, B^T layout [K][Cout][Cin]) ----------
__global__ void repack_qkvw(const float* __restrict__ wq, const float* __restrict__ wk,
                            const float* __restrict__ wv, unsigned short* __restrict__ out) {
  int i = blockIdx.x*256 + threadIdx.x;
  if (i >= NL*768*256) return;
  int c = i & 255, j = (i >> 8) % 768, l = i / (768*256);
  const float* src = (j < 256) ? wq : (j < 512) ? wk : wv;
  out[i] = f2bf(src[((size_t)l*256 + c)*256 + (j & 255)]);
}
__global__ void repack_bias(const float* __restrict__ bq, const float* __restrict__ bk,
                            const float* __restrict__ bv, float* __restrict__ out) {
  int i = blockIdx.x*256 + threadIdx.x;
  if (i >= NL*768) return;
  int j = i % 768, l = i / 768;
  const float* src = (j < 256) ? bq : (j < 512) ? bk : bv;
  out[i] = src[l*256 + (j & 255)];
}
__global__ void repack_wo(const float* __restrict__ wo, unsigned short* __restrict__ out) {
  int i = blockIdx.x*256 + threadIdx.x;
  if (i >= NL*256*256) return;
  int c = i & 255, j = (i >> 8) & 255, l = i >> 16;
  out[i] = f2bf(wo[((size_t)l*256 + c)*256 + j]);
}
__global__ void repack_c1(const float* __restrict__ w, unsigned short* __restrict__ out) {
  int i = blockIdx.x*256 + threadIdx.x;
  if (i >= NL*9*1024*256) return;
  int c = i & 255; int rest = i >> 8;
  int f = rest & 1023; int rest2 = rest >> 10;
  int k = rest2 % 9, l = rest2 / 9;
  out[i] = f2bf(w[(((size_t)l*1024 + f)*256 + c)*9 + k]);
}
__global__ void repack_c2(const float* __restrict__ w, unsigned short* __restrict__ out) {
  int i = blockIdx.x*256 + threadIdx.x;
  if (i >= NL*9*256*1024) return;
  int f = i & 1023; int rest = i >> 10;
  int d = rest & 255; int rest2 = rest >> 8;
  int k = rest2 % 9, l = rest2 / 9;
  out[i] = f2bf(w[(((size_t)l*256 + d)*1024 + f)*9 + k]);
}
__global__ void zero_halo(unsigned short* __restrict__ xb, unsigned short* __restrict__ hb) {
  int i = blockIdx.x*256 + threadIdx.x;
  if (i < 65536) {
    int b = i >> 11, r = (i >> 8) & 7, c = i & 255;
    int row = (r < 4) ? r : (512 + r);
    xb[((size_t)b*TXP + row)*256 + c] = 0;
  } else {
    int j = i - 65536;
    if (j < 262144) {
      int b = j >> 13, r = (j >> 10) & 7, c = j & 1023;
      int row = (r < 4) ? r : (512 + r);
      hb[((size_t)b*TXP + row)*1024 + c] = 0;
    }
  }
}

// ---------- embedding ----------
__global__ __launch_bounds__(256) void embed_kernel(const int* __restrict__ tok,
    const float* __restrict__ emb, const float* __restrict__ pos,
    unsigned short* __restrict__ xbo /* pre-offset +4 rows */) {
  int row = blockIdx.x*4 + (threadIdx.x >> 6);
  int t = row & 511, b = row >> 9;
  int lane = threadIdx.x & 63;
  int tk = tok[row];
  f32x4 e = *(const f32x4*)(emb + (size_t)tk*256 + lane*4);
  f32x4 p = *(const f32x4*)(pos + (size_t)t*256 + lane*4);
  f32x4 v;
#pragma unroll
  for (int i = 0; i < 4; i++) v[i] = e[i] + p[i];
  store_bf16x4(xbo + ((size_t)b*TXP + t)*256 + lane*4, v);
}

// ---------- generalized bf16 MFMA GEMM --------------------------------------
// out[t][f] = sum_k sum_c A[b,h][t+k][c] * W[b,h][k*Cout + f][c]   (+ epilogue)
// Structure (pipeline exonerated by R5 root-cause: NaN was vT aliasing):
//  - LDS swizzle: 16B group g of row stored at slot g ^ ((row>>1)&3), applied
//    on the GLOBAL source addr (linear LDS dest, rule both-sides). Kills the
//    8-way bank conflict of linear [row][32ch] frag reads -> 2-way (free).
//  - raw s_barrier + vmcnt(0) drains (no counted-FIFO assumptions).
//  - KS==1: A/W double-buffered across c0 chunks; prefetch-next right after
//    the barrier so DMA overlaps the MFMA block. 1 barrier per chunk.
//  - KS==9: A-halo staged once per c0 chunk (192-row As, rows >135 slack);
//    W double-buffered 1-deep. 1 barrier/phase + 1 restage barrier.
//  - tskip: drop t-blocks that only produce pad rows (t0 >= sl[b]+margin).
//  - maskmode && f0>=sl[b]: skip K-loop entirely; epilogue fills NEG.
template<int KS>
__global__ __launch_bounds__(256) void gemm_mfma(
    const unsigned short* __restrict__ A, long long AbO, long long AhO, int Astr,
    const unsigned short* __restrict__ W, long long WbO, long long WhO, int Wstr,
    const float* __restrict__ bias,
    float* __restrict__ O32, long long O32bO, int O32str,
    unsigned short* __restrict__ O16, long long O16bO, long long O16hO, int O16str,
    int Cin, int Cout, int relu, int H,
    const int* __restrict__ sl, float scale, int maskmode,
    const int* __restrict__ tskip, int tmargin) {
  constexpr int ASZ = (KS == 9) ? 6144 : 8192;   // shorts
  constexpr int WSZ = 8192;
  __shared__ unsigned short As[ASZ];
  __shared__ unsigned short Ws[WSZ];
  const int tid = threadIdx.x;
  int b, h;
  if (H == 2) { b = blockIdx.z >> 1; h = blockIdx.z & 1; }
  else        { b = blockIdx.z;      h = 0; }
  const int t0 = blockIdx.x * 128;
  const int f0 = blockIdx.y * 128;
  if (tskip && t0 >= tskip[b] + tmargin) return;   // block-uniform, pre-barrier
  const int slb = maskmode ? sl[b] : 0;
  const unsigned short* Ab = A + (size_t)b * AbO + (size_t)h * AhO;
  const unsigned short* Wb = W + (size_t)b * WbO + (size_t)h * WhO;
  const int lane = tid & 63, w = tid >> 6;
  const int wt = (w & 1) << 6, wf = (w >> 1) << 6;
  const int lr = lane & 15, lh = lane >> 4;        // lh = 16B col-group 0..3
  const int r0 = tid >> 2, cq = tid & 3;
  f32x4 zed = {0.f, 0.f, 0.f, 0.f};
  f32x4 acc[4][4];
#pragma unroll
  for (int i = 0; i < 4; i++)
#pragma unroll
    for (int j = 0; j < 4; j++) acc[i][j] = zed;

  // swizzled frag read: 16B group lh of row -> stored at slot lh ^ ((row>>1)&3)
  auto rdfrag = [&](const unsigned short* base, int row) -> short8 {
    return *(const short8*)&base[row*32 + (((lh ^ (row >> 1)) & 3) << 3)];
  };

  const bool skipK = maskmode && (f0 >= slb);
  if (!skipK) {
    const unsigned short* Arow = Ab + (size_t)t0 * Astr;
    if constexpr (KS == 1) {
      const int nC = Cin >> 5;
      const unsigned short* Wrow = Wb + (size_t)f0 * Wstr;
      auto st1 = [&](int c, int buf) {
        const int cc = c << 5;
#pragma unroll
        for (int j = 0; j < 2; ++j) {
          const int rl = j*64 + r0;
          const int cs = ((cq ^ (rl >> 1)) & 3) << 3;  // inverse-swz source
          gl_lds16(Arow + (size_t)rl*Astr + cc + cs, As + buf*4096 + j*2048 + (size_t)tid*8);
          gl_lds16(Wrow + (size_t)rl*Wstr + cc + cs, Ws + buf*4096 + j*2048 + (size_t)tid*8);
        }
      };
      st1(0, 0);
      for (int c = 0; c < nC; ++c) {
        asm volatile("s_waitcnt vmcnt(0)" ::: "memory");  // chunk c DMA done
        __builtin_amdgcn_s_barrier();
        asm volatile("" ::: "memory");
        if (c + 1 < nC) st1(c + 1, (c + 1) & 1);          // DMA overlaps MFMA below
        const unsigned short* Ask = As + (c & 1)*4096;
        const unsigned short* Wsk = Ws + (c & 1)*4096;
        short8 af[4], bfv[4];
#pragma unroll
        for (int mt = 0; mt < 4; mt++) af[mt]  = rdfrag(Ask, wt + mt*16 + lr);
#pragma unroll
        for (int nt = 0; nt < 4; nt++) bfv[nt] = rdfrag(Wsk, wf + nt*16 + lr);
#pragma unroll
        for (int mt = 0; mt < 4; mt++)
#pragma unroll
          for (int nt = 0; nt < 4; nt++)
            acc[mt][nt] = __builtin_amdgcn_mfma_f32_16x16x32_bf16(af[mt], bfv[nt], acc[mt][nt], 0, 0, 0);
      }
    } else {  // KS == 9
      auto stA9 = [&](int c0) {      // rows 0..191 (136..191 slack), 3 uniform instrs
#pragma unroll
        for (int j = 0; j < 3; ++j) {
          const int rl = j*64 + r0;
          const int cs = ((cq ^ (rl >> 1)) & 3) << 3;
          gl_lds16(Arow + (size_t)rl*Astr + c0 + cs, As + j*2048 + (size_t)tid*8);
        }
      };
      auto stW9 = [&](int c0, int k, int buf) {  // 2 uniform instrs
        const unsigned short* Wk = Wb + ((size_t)k * Cout + f0) * Wstr + c0;
#pragma unroll
        for (int j = 0; j < 2; ++j) {
          const int rl = j*64 + r0;
          const int cs = ((cq ^ (rl >> 1)) & 3) << 3;
          gl_lds16(Wk + (size_t)rl*Wstr + cs, Ws + buf*4096 + j*2048 + (size_t)tid*8);
        }
      };
      stA9(0); stW9(0, 0, 0);
      for (int c0 = 0; c0 < Cin; c0 += 32) {
        const bool last = (c0 + 32 >= Cin);
#pragma unroll
        for (int k = 0; k < 9; ++k) {
          asm volatile("s_waitcnt vmcnt(0)" ::: "memory");   // phase's tile DMA done
          __builtin_amdgcn_s_barrier();
          asm volatile("" ::: "memory");
          if (k < 8) stW9(c0, k + 1, (k + 1) & 1);           // overlaps MFMA below
          const unsigned short* Wsk = Ws + (k & 1)*4096;
          short8 af[4], bfv[4];
#pragma unroll
          for (int mt = 0; mt < 4; mt++) af[mt]  = rdfrag(As, k + wt + mt*16 + lr);
#pragma unroll
          for (int nt = 0; nt < 4; nt++) bfv[nt] = rdfrag(Wsk, wf + nt*16 + lr);
          if (k == 8 && !last) {
            // my As/Ws reads are in regs; fence, then all waves' reads done
            asm volatile("s_waitcnt lgkmcnt(0)" ::: "memory");
            __builtin_amdgcn_s_barrier();
            asm volatile("" ::: "memory");
            stA9(c0 + 32);            // DMA overlaps the 16 MFMAs below
            stW9(c0 + 32, 0, 0);      // next c0 iter k=0 reads buf 0
          }
#pragma unroll
          for (int mt = 0; mt < 4; mt++)
#pragma unroll
            for (int nt = 0; nt < 4; nt++)
              acc[mt][nt] = __builtin_amdgcn_mfma_f32_16x16x32_bf16(af[mt], bfv[nt], acc[mt][nt], 0, 0, 0);
        }
      }
    }
  }
  // epilogue: D row t = (lane>>4)*4+r, col f = lane&15
#pragma unroll
  for (int mt = 0; mt < 4; mt++) {
    int trow = t0 + wt + mt*16 + lh*4;
#pragma unroll
    for (int nt = 0; nt < 4; nt++) {
      int f = f0 + wf + nt*16 + lr;
      float bb = (!maskmode && bias) ? bias[f] : 0.f;
#pragma unroll
      for (int r = 0; r < 4; r++) {
        float v;
        if (maskmode) {
          v = acc[mt][nt][r] * scale;
          if (f >= slb) v = NEGF;
        } else {
          v = acc[mt][nt][r] + bb;
          if (relu) v = fmaxf(v, 0.f);
        }
        if (O32) O32[(size_t)b*O32bO + (size_t)(trow + r)*O32str + f] = v;
        if (O16) O16[(size_t)b*O16bO + (size_t)h*O16hO + (size_t)(trow + r)*O16str + f] = f2bf(v);
      }
    }
  }
}

// ---------- V transpose: VT[bh][d][t] <- qkv V section; zero t >= sl[b] ------
__global__ __launch_bounds__(256) void vtrans_kernel(const unsigned short* __restrict__ qkv,
    const int* __restrict__ sl, unsigned short* __restrict__ VT) {
  const int z = blockIdx.z, b = z >> 1, h = z & 1;
  const int t0 = blockIdx.x << 5, d0 = blockIdx.y << 5;
  __shared__ unsigned short tile[32][33];
  const int tx = threadIdx.x, ty = threadIdx.y;
  const int slb = sl[b];
  const unsigned short* src = qkv + (size_t)b*TX*768 + 512 + h*DK;
#pragma unroll
  for (int i = 0; i < 4; i++)
    tile[ty + i*8][tx] = src[(size_t)(t0 + ty + i*8)*768 + d0 + tx];
  __syncthreads();
#pragma unroll
  for (int i = 0; i < 4; i++) {
    unsigned short v = (t0 + tx < slb) ? tile[tx][ty + i*8] : (unsigned short)0;
    VT[((size_t)z*DK + d0 + ty + i*8)*512 + t0 + tx] = v;
  }
}

// ---------- softmax over bf16 score rows ----------
__global__ __launch_bounds__(256) void softmax_kernel(unsigned short* __restrict__ S) {
  const int row = blockIdx.x*4 + (threadIdx.x >> 6);
  const int lane = threadIdx.x & 63;
  unsigned short* p = S + (size_t)row*512 + lane*8;
  short8 raw = *(const short8*)p;
  float a[8];
#pragma unroll
  for (int i = 0; i < 8; i++) a[i] = bf2f((unsigned short)raw[i]);
  float m = a[0];
#pragma unroll
  for (int i = 1; i < 8; i++) m = fmaxf(m, a[i]);
  m = wmax(m);
  float s = 0.f;
#pragma unroll
  for (int i = 0; i < 8; i++) { a[i] = __expf(a[i]-m); s += a[i]; }
  s = wsum(s);
  float inv = 1.f / s;
  short8 o;
#pragma unroll
  for (int i = 0; i < 8; i++) o[i] = (short)f2bf(a[i] * inv);
  *(short8*)p = o;
}

// ---------- residual(bf16) + layernorm + pad-mask; rewrites bf16 padded xb ----------
__global__ __launch_bounds__(256) void ln_kernel(const float* __restrict__ tin,
    const float* __restrict__ g, const float* __restrict__ bt, const int* __restrict__ sl,
    unsigned short* __restrict__ xbo /* pre-offset +4 rows */) {
  const int row = blockIdx.x*4 + (threadIdx.x >> 6);
  const int b = row >> 9, t = row & 511;
  const int lane = threadIdx.x & 63;
  unsigned short* xp = xbo + ((size_t)b*TXP + t)*256 + lane*4;
  f32x4 tv = *(const f32x4*)(tin + (size_t)row*256 + lane*4);
  ushort4v rv4 = *(const ushort4v*)xp;
  f32x4 s; float su = 0.f, sq = 0.f;
#pragma unroll
  for (int i = 0; i < 4; i++) {
    s[i] = tv[i] + bf2f(rv4[i]);
    su += s[i]; sq += s[i]*s[i];
  }
  su = wsum(su); sq = wsum(sq);
  float mean = su * (1.f/256.f);
  float var = fmaxf(sq * (1.f/256.f) - mean*mean, 0.f);
  float rs = rsqrtf(var + 1e-5f);
  f32x4 gg = *(const f32x4*)(g + lane*4);
  f32x4 bb = *(const f32x4*)(bt + lane*4);
  bool padr = (t >= sl[b]);
  f32x4 y;
#pragma unroll
  for (int i = 0; i < 4; i++) {
    float yy = (s[i]-mean)*rs*gg[i] + bb[i];
    y[i] = padr ? 0.f : yy;
  }
  store_bf16x4(xp, y);
}

// ---------- MAS: masked transpose of value ----------
__global__ __launch_bounds__(256) void transpose_mask(const float* __restrict__ value,
    const int* __restrict__ sl, const int* __restrict__ ml, float* __restrict__ vT) {
  const int b = blockIdx.z;
  const int x0 = blockIdx.y << 5, y0 = blockIdx.x << 5;
  __shared__ float tile[32][33];
  const int tx = threadIdx.x, ty = threadIdx.y;
  const int slb = sl[b], mlb = ml[b];
#pragma unroll
  for (int i = 0; i < 4; i++) {
    int x = x0 + ty + i*8, y = y0 + tx;
    float v = value[((size_t)b*TX + x)*TY + y];
    tile[ty + i*8][tx] = (x < slb && y < mlb) ? v : 0.f;
  }
  __syncthreads();
#pragma unroll
  for (int i = 0; i < 4; i++) {
    int y = y0 + ty + i*8, x = x0 + tx;
    vT[((size_t)b*TY + y)*TX + x] = tile[tx][ty + i*8];
  }
}

// ---------- fused MAS DP (forward + backward), one wave per batch ----------
template<bool RAMP>
__device__ __forceinline__ void dp_comp8(
    int jb, const float* valbuf, unsigned long long* dll,
    float v[8], int lane, int xbase, unsigned int vmask, unsigned int fmask,
    bool lane0) {
  unsigned int w0 = 0, w1 = 0;
#pragma unroll
  for (int u = 0; u < 8; ++u) {
    const int j = jb*8 + u;
    f32x4 a0 = *(const f32x4*)(valbuf + u*512 + lane*8);
    f32x4 a1 = *(const f32x4*)(valbuf + u*512 + lane*8 + 4);
    float vp = lane_shr1(v[7]);          // old v[7] of lane-1
    if (lane0) vp = NEGF;
    unsigned int ge = 0;
#pragma unroll
    for (int i = 7; i >= 1; --i) {       // descending: v[i-1] still old
      unsigned int g = (v[i] >= v[i-1]) ? 1u : 0u;
      ge = (ge << 1) | g;
      float nv = fmaxf(v[i], v[i-1]) + ((i < 4) ? a0[i] : a1[i-4]);
      if (RAMP) v[i] = (xbase + i <= j) ? nv : NEGF;
      else      v[i] = nv;
    }
    {
      unsigned int g = (v[0] >= vp) ? 1u : 0u;
      ge = (ge << 1) | g;
      float nv = fmaxf(v[0], vp) + a0[0];
      if (RAMP) v[0] = (xbase <= j) ? nv : NEGF;
      else      v[0] = nv;
    }
    unsigned int byt = (ge & vmask) | fmask;   // force-1 where x >= slb
    if (u < 4) w0 |= byt << (8*u); else w1 |= byt << (8*(u-4));
  }
  dll[jb*64 + lane] = ((unsigned long long)w1 << 32) | w0;
}

__global__ __launch_bounds__(64, 1) void dp_fused(const float* __restrict__ vT,
    const int* __restrict__ sl, const int* __restrict__ ml,
    int* __restrict__ idxout) {
  __shared__ float sval[3*4096];              // 3 x (8 j x 512 x) f32 = 48 KB
  __shared__ unsigned long long dll[TY*8];    // direction bitmap, 64 KB
  unsigned char* dld = (unsigned char*)dll;
  const int b = blockIdx.x, lane = threadIdx.x;
  const int slb = sl[b], mlb = ml[b];
  const float* vb = vT + (size_t)b*TY*TX;
  const int xbase = lane*8;
  const bool lane0 = (lane == 0);
  unsigned int vmaskv = 0;
#pragma unroll
  for (int i = 0; i < 8; ++i) if (xbase + i < slb) vmaskv |= (1u << i);
  const unsigned int fmaskv = (~vmaskv) & 0xffu;
  float v[8];
#pragma unroll
  for (int i = 0; i < 8; ++i) v[i] = 0.f;
  const int jbEnd = (mlb + 7) >> 3;           // in [64,128]

  auto stage = [&](int jb, float* buf) {      // 16 async loads, 16B/lane
    const float* src = vb + (size_t)jb*8*TX;
#pragma unroll
    for (int u = 0; u < 8; ++u) {
      gl_lds16f(src + u*TX + lane*4,       buf + u*512);
      gl_lds16f(src + u*TX + 256 + lane*4, buf + u*512 + 256);
    }
  };
  stage(0, sval);
  stage(1, sval + 4096);
  stage(2, sval + 8192);
  int buf = 0;
  int jb = 0;
  for (; jb < 64; ++jb) {
    if (jb + 2 < jbEnd)      asm volatile("s_waitcnt vmcnt(32)" ::: "memory");
    else if (jb + 1 < jbEnd) asm volatile("s_waitcnt vmcnt(16)" ::: "memory");
    else                     asm volatile("s_waitcnt vmcnt(0)"  ::: "memory");
    float* vbuf = sval + buf*4096;
    dp_comp8<true>(jb, vbuf, dll, v, lane, xbase, vmaskv, fmaskv, lane0);
    __builtin_amdgcn_sched_barrier(0);
    if (jb + 3 < jbEnd) stage(jb + 3, vbuf);
    buf = (buf == 2) ? 0 : buf + 1;
  }
  for (; jb < jbEnd; ++jb) {
    if (jb + 2 < jbEnd)      asm volatile("s_waitcnt vmcnt(32)" ::: "memory");
    else if (jb + 1 < jbEnd) asm volatile("s_waitcnt vmcnt(16)" ::: "memory");
    else                     asm volatile("s_waitcnt vmcnt(0)"  ::: "memory");
    float* vbuf = sval + buf*4096;
    dp_comp8<false>(jb, vbuf, dll, v, lane, xbase, vmaskv, fmaskv, lane0);
    __builtin_amdgcn_sched_barrier(0);
    if (jb + 3 < jbEnd) stage(jb + 3, vbuf);
    buf = (buf == 2) ? 0 : buf + 1;
  }
  for (int jj = mlb + lane; jj < TY; jj += 64) idxout[b*TY + jj] = -1;
  if (lane0) {
    int* ob = idxout + b*TY;
    int idx = slb - 1;
    int j = mlb - 1;
    while (j >= 6) {
      int o0 = idx >> 3;
      int o1 = (o0 > 0) ? (o0 - 1) : 0;
      unsigned int bc[7], ba[7];
#pragma unroll
      for (int s = 0; s < 7; ++s) {       // 14 independent ds_read_u8
        int r = j - s;
        int rbase = ((r >> 3) << 9) + (r & 7);
        bc[s] = dld[rbase + o0*8];
        ba[s] = dld[rbase + o1*8];
      }
#pragma unroll
      for (int s = 0; s < 7; ++s) {
        ob[j - s] = idx;
        unsigned int byt = ((idx >> 3) == o0) ? bc[s] : ba[s];
        idx += (int)((byt >> (idx & 7)) & 1u) - 1;
      }
      j -= 7;
    }
    while (j >= 0) {
      ob[j] = idx;
      unsigned int byt = dld[((j >> 3) << 9) + (j & 7) + (idx >> 3)*8];
      idx += (int)((byt >> (idx & 7)) & 1u) - 1;
      --j;
    }
  }
}

// ---------- final gather (bf16 activations -> f32 out) ----------
__global__ __launch_bounds__(256) void gather_kernel(const unsigned short* __restrict__ xbo,
    const int* __restrict__ idxout, float* __restrict__ out) {
  const int row = blockIdx.x*4 + (threadIdx.x >> 6);
  const int lane = threadIdx.x & 63;
  const int b = row >> 10;
  const int idx = idxout[row];
  f32x4 v;
  if (idx >= 0) {
    ushort4v r = *(const ushort4v*)(xbo + ((size_t)b*TXP + idx)*256 + lane*4);
#pragma unroll
    for (int i = 0; i < 4; i++) v[i] = bf2f(r[i]);
  } else { v[0]=0.f; v[1]=0.f; v[2]=0.f; v[3]=0.f; }
  *(f32x4*)(out + (size_t)row*256 + lane*4) = v;
}

// ---------- launch ----------
extern "C" void kernel_launch(void* const* d_in, const int* in_sizes, int n_in,
                              void* d_out, int out_size, void* d_ws, size_t ws_size,
                              hipStream_t stream) {
  const int*   tokens = (const int*)d_in[0];
  const int*   sl     = (const int*)d_in[1];
  const int*   ml     = (const int*)d_in[2];
  const float* value  = (const float*)d_in[3];
  const float* emb    = (const float*)d_in[4];
  const float* pos    = (const float*)d_in[5];
  const float* wq     = (const float*)d_in[6];
  const float* bq     = (const float*)d_in[7];
  const float* wk     = (const float*)d_in[8];
  const float* bk     = (const float*)d_in[9];
  const float* wv     = (const float*)d_in[10];
  const float* bv     = (const float*)d_in[11];
  const float* wo     = (const float*)d_in[12];
  const float* bo     = (const float*)d_in[13];
  const float* ln1g   = (const float*)d_in[14];
  const float* ln1bb  = (const float*)d_in[15];
  const float* c1w    = (const float*)d_in[16];
  const float* c1b    = (const float*)d_in[17];
  const float* c2w    = (const float*)d_in[18];
  const float* c2b    = (const float*)d_in[19];
  const float* ln2g   = (const float*)d_in[20];
  const float* ln2bb  = (const float*)d_in[21];

  char* w8 = (char*)d_ws;
  unsigned short* xb     = (unsigned short*)(w8 + OFF_XB);
  unsigned short* hb     = (unsigned short*)(w8 + OFF_HB);
  unsigned short* qkvb   = (unsigned short*)(w8 + OFF_QKV);
  unsigned short* S      = (unsigned short*)(w8 + OFF_S);
  float*          vT     = (float*)(w8 + OFF_HB);            // MAS-phase alias
  unsigned short* VT     = (unsigned short*)(w8 + OFF_T1);   // attention-phase alias
  unsigned short* ao     = (unsigned short*)(w8 + OFF_AO);
  float*          T1     = (float*)(w8 + OFF_T1);
  unsigned short* wqkv_r = (unsigned short*)(w8 + OFF_WQKV);
  float*          bqkv   = (float*)(w8 + OFF_BQKV);
  unsigned short* wo_r   = (unsigned short*)(w8 + OFF_WO);
  unsigned short* wt1r   = (unsigned short*)(w8 + OFF_WT1);
  unsigned short* wt2r   = (unsigned short*)(w8 + OFF_WT2);
  int*            idxout = (int*)(w8 + OFF_IDX);
  float*          out    = (float*)d_out;

  const float scale = 0.08838834764831843f;  // 1/sqrt(128)

  // weight repack
  repack_qkvw<<<(NL*768*256 + 255)/256, 256, 0, stream>>>(wq, wk, wv, wqkv_r);
  repack_bias<<<(NL*768 + 255)/256, 256, 0, stream>>>(bq, bk, bv, bqkv);
  repack_wo<<<(NL*256*256 + 255)/256, 256, 0, stream>>>(wo, wo_r);
  repack_c1<<<(NL*9*1024*256 + 255)/256, 256, 0, stream>>>(c1w, wt1r);
  repack_c2<<<(NL*9*256*1024 + 255)/256, 256, 0, stream>>>(c2w, wt2r);

  // monotonic alignment search first (vT aliases HB+QKV+part of S!)
  transpose_mask<<<dim3(32, 16, 32), dim3(32, 8), 0, stream>>>(value, sl, ml, vT);
  dp_fused<<<32, 64, 0, stream>>>(vT, sl, ml, idxout);

  // qkvb must be finite everywhere (skip-blocks leave rows >= sl unwritten).
  // MUST be issued AFTER dp_fused: vT covers this region (R2-R4 NaN bug).
  hipMemsetAsync(qkvb, 0, SZ_QKV, stream);

  // halo zero + embedding
  zero_halo<<<(327680 + 255)/256, 256, 0, stream>>>(xb, hb);
  embed_kernel<<<4096, 256, 0, stream>>>(tokens, emb, pos, xb + 4*256);

  // encoder layers
  for (int l = 0; l < NL; l++) {
    // QKV projection: [B] x: 512x256 @ 256x768 -> qkvb bf16
    gemm_mfma<1><<<dim3(4, 6, 32), 256, 0, stream>>>(
        xb + 4*256, (long long)TXP*256, 0, 256,
        wqkv_r + (size_t)l*768*256, 0, 0, 256,
        bqkv + l*768,
        nullptr, 0, 0,
        qkvb, (long long)TX*768, 0, 768,
        256, 768, 0, 1, nullptr, 0.f, 0, sl, 0);
    // scores: per (b,h): Q[512x128] @ K^T -> S bf16, scale + key mask
    gemm_mfma<1><<<dim3(4, 4, 64), 256, 0, stream>>>(
        qkvb, (long long)TX*768, 128, 768,
        qkvb + 256, (long long)TX*768, 128, 768,
        nullptr,
        nullptr, 0, 0,
        S, (long long)2*512*512, (long long)512*512, 512,
        128, 512, 0, 2, sl, scale, 1, sl, 0);
    softmax_kernel<<<8192, 256, 0, stream>>>(S);
    vtrans_kernel<<<dim3(16, 4, 64), dim3(32, 8), 0, stream>>>(qkvb, sl, VT);
    // AV: per (b,h): P[512x512] @ V[512x128] (VT rows are d) -> ao bf16
    gemm_mfma<1><<<dim3(4, 1, 64), 256, 0, stream>>>(
        S, (long long)2*512*512, (long long)512*512, 512,
        VT, (long long)2*DK*512, (long long)DK*512, 512,
        nullptr,
        nullptr, 0, 0,
        ao, (long long)TX*256, 128, 256,
        512, 128, 0, 2, nullptr, 0.f, 0, sl, 0);
    // out-proj -> T1 f32 (after AV: T1/VT alias hand-off)
    gemm_mfma<1><<<dim3(4, 2, 32), 256, 0, stream>>>(
        ao, (long long)TX*256, 0, 256,
        wo_r + (size_t)l*256*256, 0, 0, 256,
        bo + l*256,
        T1, (long long)TX*256, 256,
        nullptr, 0, 0, 0,
        256, 256, 0, 1, nullptr, 0.f, 0, sl, 0);
    ln_kernel<<<4096, 256, 0, stream>>>(T1, ln1g + l*256, ln1bb + l*256, sl, xb + 4*256);
    // conv1 (K=9) -> hb bf16 (relu); outputs needed for rows < sl+4
    gemm_mfma<9><<<dim3(4, 8, 32), 256, 0, stream>>>(
        xb, (long long)TXP*256, 0, 256,
        wt1r + (size_t)l*9*1024*256, 0, 0, 256,
        c1b + l*1024,
        nullptr, 0, 0,
        hb + 4*1024, (long long)TXP*1024, 0, 1024,
        256, 1024, 1, 1, nullptr, 0.f, 0, sl, 4);
    // conv2 (K=9) -> T1 f32
    gemm_mfma<9><<<dim3(4, 2, 32), 256, 0, stream>>>(
        hb, (long long)TXP*1024, 0, 1024,
        wt2r + (size_t)l*9*256*1024, 0, 0, 1024,
        c2b + l*256,
        T1, (long long)TX*256, 256,
        nullptr, 0, 0, 0,
        1024, 256, 0, 1, nullptr, 0.f, 0, sl, 0);
    ln_kernel<<<4096, 256, 0, stream>>>(T1, ln2g + l*256, ln2bb + l*256, sl, xb + 4*256);
  }

  // expand via alignment path
  gather_kernel<<<8192, 256, 0, stream>>>(xb + 4*256, idxout, out);
  (void)in_sizes; (void)n_in; (void)out_size; (void)ws_size;
}

// Round 7
// 1950.057 us; speedup vs baseline: 1.1283x; 1.0402x over previous
//
#include <hip/hip_runtime.h>

#define B_  32
#define TX  512
#define TY  1024
#define D_  256
#define H_  2
#define DK  128
#define FN  1024
#define NL  4
#define TXP 520        // TX + 8 halo rows (4 each side) for K=9 convs
#define NEGF (-1e9f)

typedef __attribute__((ext_vector_type(4))) float f32x4;
typedef __attribute__((ext_vector_type(8))) short short8;
typedef __attribute__((ext_vector_type(4))) unsigned short ushort4v;

typedef __attribute__((address_space(3))) unsigned int lds_u32;
typedef __attribute__((address_space(1))) const unsigned int glb_u32;

// ---------- helpers ----------
__device__ __forceinline__ unsigned short f2bf(float x) {
  unsigned int u = __builtin_bit_cast(unsigned int, x);
  u += 0x7fffu + ((u >> 16) & 1u);           // RNE
  return (unsigned short)(u >> 16);
}
__device__ __forceinline__ float bf2f(unsigned short x) {
  unsigned int u = ((unsigned int)x) << 16;
  return __builtin_bit_cast(float, u);
}
__device__ __forceinline__ void store_bf16x4(unsigned short* p, f32x4 v) {
  ushort4v o; o[0]=f2bf(v[0]); o[1]=f2bf(v[1]); o[2]=f2bf(v[2]); o[3]=f2bf(v[3]);
  *(ushort4v*)p = o;
}
__device__ __forceinline__ float wsum(float v) {
#pragma unroll
  for (int i = 1; i < 64; i <<= 1) v += __shfl_xor(v, i, 64);
  return v;
}
__device__ __forceinline__ float wmax(float v) {
#pragma unroll
  for (int i = 1; i < 64; i <<= 1) v = fmaxf(v, __shfl_xor(v, i, 64));
  return v;
}
// async global->LDS, 16B per lane. LDS dest is wave-uniform base + lane*16.
__device__ __forceinline__ void gl_lds16(const unsigned short* g, unsigned short* l) {
  __builtin_amdgcn_global_load_lds((glb_u32*)g, (lds_u32*)l, 16, 0, 0);
}
__device__ __forceinline__ void gl_lds16f(const float* g, float* l) {
  __builtin_amdgcn_global_load_lds((glb_u32*)g, (lds_u32*)l, 16, 0, 0);
}
// lane i <- lane i-1 (wave_shr:1 DPP); lane 0 gets 0 (bound_ctrl off, old=0)
__device__ __forceinline__ float lane_shr1(float x) {
  int r = __builtin_amdgcn_update_dpp(0, __builtin_bit_cast(int, x), 0x138, 0xF, 0xF, false);
  return __builtin_bit_cast(float, r);
}

// ---------- workspace layout (bytes), total ~169 MB ----------
static const size_t OFF_XB   = 0;
static const size_t SZ_XB    = (size_t)B_*TXP*D_*2;      // bf16 padded activations
static const size_t OFF_HB   = OFF_XB + SZ_XB;
static const size_t SZ_HB    = (size_t)B_*TXP*FN*2;      // bf16 padded conv hidden
static const size_t OFF_QKV  = OFF_HB + SZ_HB;
static const size_t SZ_QKV   = (size_t)B_*TX*768*2;      // q|k|v bf16
static const size_t OFF_S    = OFF_QKV + SZ_QKV;
static const size_t SZ_S     = (size_t)B_*H_*TX*TX*2;    // scores bf16
static const size_t OFF_AO   = OFF_S + SZ_S;
static const size_t SZ_AO    = (size_t)B_*TX*D_*2;       // attn out bf16
static const size_t OFF_T1   = OFF_AO + SZ_AO;
static const size_t SZ_T1    = (size_t)B_*TX*D_*4;       // pre-LN f32
static const size_t OFF_WQKV = OFF_T1 + SZ_T1;
static const size_t SZ_WQKV  = (size_t)NL*768*256*2;
static const size_t OFF_BQKV = OFF_WQKV + SZ_WQKV;
static const size_t SZ_BQKV  = (size_t)NL*768*4;
static const size_t OFF_WO   = OFF_BQKV + SZ_BQKV;
static const size_t SZ_WO    = (size_t)NL*256*256*2;
static const size_t OFF_WT1  = OFF_WO + SZ_WO;
static const size_t SZ_WT1   = (size_t)NL*9*1024*256*2;
static const size_t OFF_WT2  = OFF_WT1 + SZ_WT1;
static const size_t SZ_WT2   = SZ_WT1;
static const size_t OFF_DIRS = OFF_WT2 + SZ_WT2;         // (unused scratch)
static const size_t SZ_DIRS  = (size_t)B_*TY*64;
static const size_t OFF_IDX  = OFF_DIRS + SZ_DIRS;
// phase-local aliases:
//   vT (f32, 64 MB!) at OFF_HB - MAS only. NOTE: 64 MB > SZ_HB (34 MB) — vT
//     deliberately spills across ALL of OFF_QKV and 7.8 MB into OFF_S. Any
//     init of qkvb/S must happen AFTER dp_fused (R2-R4 NaN bug: memset(qkvb)
//     before transpose_mask was overwritten by vT f32 data whose low halves
//     decode as NaN bf16; AV's P*V sum transported the NaN into valid rows).
//   VT (bf16, 8.4 MB) at OFF_T1 - attention-phase V^T; T1 dead between ln read
//     (prev layer) and out-proj write (after AV). NOTE: must NOT overlap HB.

// ---------- weight repacks (f32 inputs -> bf16, B^T layout [K][Cout][Cin]) ----------
__global__ void repack_qkvw(const float* __restrict__ wq, const float* __restrict__ wk,
                            const float* __restrict__ wv, unsigned short* __restrict__ out) {
  int i = blockIdx.x*256 + threadIdx.x;
  if (i >= NL*768*256) return;
  int c = i & 255, j = (i >> 8) % 768, l = i / (768*256);
  const float* src = (j < 256) ? wq : (j < 512) ? wk : wv;
  out[i] = f2bf(src[((size_t)l*256 + c)*256 + (j & 255)]);
}
__global__ void repack_bias(const float* __restrict__ bq, const float* __restrict__ bk,
                            const float* __restrict__ bv, float* __restrict__ out) {
  int i = blockIdx.x*256 + threadIdx.x;
  if (i >= NL*768) return;
  int j = i % 768, l = i / 768;
  const float* src = (j < 256) ? bq : (j < 512) ? bk : bv;
  out[i] = src[l*256 + (j & 255)];
}
__global__ void repack_wo(const float* __restrict__ wo, unsigned short* __restrict__ out) {
  int i = blockIdx.x*256 + threadIdx.x;
  if (i >= NL*256*256) return;
  int c = i & 255, j = (i >> 8) & 255, l = i >> 16;
  out[i] = f2bf(wo[((size_t)l*256 + c)*256 + j]);
}
__global__ void repack_c1(const float* __restrict__ w, unsigned short* __restrict__ out) {
  int i = blockIdx.x*256 + threadIdx.x;
  if (i >= NL*9*1024*256) return;
  int c = i & 255; int rest = i >> 8;
  int f = rest & 1023; int rest2 = rest >> 10;
  int k = rest2 % 9, l = rest2 / 9;
  out[i] = f2bf(w[(((size_t)l*1024 + f)*256 + c)*9 + k]);
}
__global__ void repack_c2(const float* __restrict__ w, unsigned short* __restrict__ out) {
  int i = blockIdx.x*256 + threadIdx.x;
  if (i >= NL*9*256*1024) return;
  int f = i & 1023; int rest = i >> 10;
  int d = rest & 255; int rest2 = rest >> 8;
  int k = rest2 % 9, l = rest2 / 9;
  out[i] = f2bf(w[(((size_t)l*256 + d)*1024 + f)*9 + k]);
}
__global__ void zero_halo(unsigned short* __restrict__ xb, unsigned short* __restrict__ hb) {
  int i = blockIdx.x*256 + threadIdx.x;
  if (i < 65536) {
    int b = i >> 11, r = (i >> 8) & 7, c = i & 255;
    int row = (r < 4) ? r : (512 + r);
    xb[((size_t)b*TXP + row)*256 + c] = 0;
  } else {
    int j = i - 65536;
    if (j < 262144) {
      int b = j >> 13, r = (j >> 10) & 7, c = j & 1023;
      int row = (r < 4) ? r : (512 + r);
      hb[((size_t)b*TXP + row)*1024 + c] = 0;
    }
  }
}

// ---------- embedding ----------
__global__ __launch_bounds__(256) void embed_kernel(const int* __restrict__ tok,
    const float* __restrict__ emb, const float* __restrict__ pos,
    unsigned short* __restrict__ xbo /* pre-offset +4 rows */) {
  int row = blockIdx.x*4 + (threadIdx.x >> 6);
  int t = row & 511, b = row >> 9;
  int lane = threadIdx.x & 63;
  int tk = tok[row];
  f32x4 e = *(const f32x4*)(emb + (size_t)tk*256 + lane*4);
  f32x4 p = *(const f32x4*)(pos + (size_t)t*256 + lane*4);
  f32x4 v;
#pragma unroll
  for (int i = 0; i < 4; i++) v[i] = e[i] + p[i];
  store_bf16x4(xbo + ((size_t)b*TXP + t)*256 + lane*4, v);
}

// ---------- generalized bf16 MFMA GEMM --------------------------------------
// out[t][f] = sum_k sum_c A[b,h][t+k][c] * W[b,h][k*Cout + f][c]   (+ epilogue)
// Structure:
//  - LDS swizzle: 16B group g of row stored at slot g ^ ((row>>1)&3), applied
//    on the GLOBAL source addr (linear LDS dest) + same XOR on ds_read.
//  - KS==1: A/W double-buffered across c0 chunks; prefetch-next after the
//    barrier so DMA overlaps MFMA. vmcnt(0) drain (only the 1-deep prefetch).
//  - KS==9 (T3+T4, R2 design exonerated by R5 root-cause): A staged once per
//    c0 chunk; W TRIPLE-buffered, 2-phase-deep prefetch, counted vmcnt(2) —
//    never 0 mid-loop. At each phase the wait targets loads issued 2 phases
//    ago (already retired) -> phase cost = barrier + MFMA, no DMA round-trip.
//    FIFO: prologue leaves A(3)+W0(2)+W1(2)=7; vmcnt(2) retires all but the
//    newest W-pair. No other vmem ops in-loop (no spills: ~170 VGPR, no cap).
//  - tskip / skipK block pruning as before.
template<int KS>
__global__ __launch_bounds__(256) void gemm_mfma(
    const unsigned short* __restrict__ A, long long AbO, long long AhO, int Astr,
    const unsigned short* __restrict__ W, long long WbO, long long WhO, int Wstr,
    const float* __restrict__ bias,
    float* __restrict__ O32, long long O32bO, int O32str,
    unsigned short* __restrict__ O16, long long O16bO, long long O16hO, int O16str,
    int Cin, int Cout, int relu, int H,
    const int* __restrict__ sl, float scale, int maskmode,
    const int* __restrict__ tskip, int tmargin) {
  constexpr int ASZ = (KS == 9) ? 6144 : 8192;    // shorts
  constexpr int WSZ = (KS == 9) ? 12288 : 8192;   // 3 bufs for KS==9
  __shared__ unsigned short As[ASZ];
  __shared__ unsigned short Ws[WSZ];
  const int tid = threadIdx.x;
  int b, h;
  if (H == 2) { b = blockIdx.z >> 1; h = blockIdx.z & 1; }
  else        { b = blockIdx.z;      h = 0; }
  const int t0 = blockIdx.x * 128;
  const int f0 = blockIdx.y * 128;
  if (tskip && t0 >= tskip[b] + tmargin) return;   // block-uniform, pre-barrier
  const int slb = maskmode ? sl[b] : 0;
  const unsigned short* Ab = A + (size_t)b * AbO + (size_t)h * AhO;
  const unsigned short* Wb = W + (size_t)b * WbO + (size_t)h * WhO;
  const int lane = tid & 63, w = tid >> 6;
  const int wt = (w & 1) << 6, wf = (w >> 1) << 6;
  const int lr = lane & 15, lh = lane >> 4;        // lh = 16B col-group 0..3
  const int r0 = tid >> 2, cq = tid & 3;
  f32x4 zed = {0.f, 0.f, 0.f, 0.f};
  f32x4 acc[4][4];
#pragma unroll
  for (int i = 0; i < 4; i++)
#pragma unroll
    for (int j = 0; j < 4; j++) acc[i][j] = zed;

  // swizzled frag read: 16B group lh of row -> stored at slot lh ^ ((row>>1)&3)
  auto rdfrag = [&](const unsigned short* base, int row) -> short8 {
    return *(const short8*)&base[row*32 + (((lh ^ (row >> 1)) & 3) << 3)];
  };

  const bool skipK = maskmode && (f0 >= slb);
  if (!skipK) {
    const unsigned short* Arow = Ab + (size_t)t0 * Astr;
    if constexpr (KS == 1) {
      const int nC = Cin >> 5;
      const unsigned short* Wrow = Wb + (size_t)f0 * Wstr;
      auto st1 = [&](int c, int buf) {
        const int cc = c << 5;
#pragma unroll
        for (int j = 0; j < 2; ++j) {
          const int rl = j*64 + r0;
          const int cs = ((cq ^ (rl >> 1)) & 3) << 3;  // inverse-swz source
          gl_lds16(Arow + (size_t)rl*Astr + cc + cs, As + buf*4096 + j*2048 + (size_t)tid*8);
          gl_lds16(Wrow + (size_t)rl*Wstr + cc + cs, Ws + buf*4096 + j*2048 + (size_t)tid*8);
        }
      };
      st1(0, 0);
      for (int c = 0; c < nC; ++c) {
        asm volatile("s_waitcnt vmcnt(0)" ::: "memory");  // chunk c DMA done
        __builtin_amdgcn_s_barrier();
        asm volatile("" ::: "memory");
        if (c + 1 < nC) st1(c + 1, (c + 1) & 1);          // DMA overlaps MFMA below
        const unsigned short* Ask = As + (c & 1)*4096;
        const unsigned short* Wsk = Ws + (c & 1)*4096;
        short8 af[4], bfv[4];
#pragma unroll
        for (int mt = 0; mt < 4; mt++) af[mt]  = rdfrag(Ask, wt + mt*16 + lr);
#pragma unroll
        for (int nt = 0; nt < 4; nt++) bfv[nt] = rdfrag(Wsk, wf + nt*16 + lr);
#pragma unroll
        for (int mt = 0; mt < 4; mt++)
#pragma unroll
          for (int nt = 0; nt < 4; nt++)
            acc[mt][nt] = __builtin_amdgcn_mfma_f32_16x16x32_bf16(af[mt], bfv[nt], acc[mt][nt], 0, 0, 0);
      }
    } else {  // KS == 9
      auto stA9 = [&](int c0) {      // rows 0..191 (136..191 slack), 3 uniform instrs
#pragma unroll
        for (int j = 0; j < 3; ++j) {
          const int rl = j*64 + r0;
          const int cs = ((cq ^ (rl >> 1)) & 3) << 3;
          gl_lds16(Arow + (size_t)rl*Astr + c0 + cs, As + j*2048 + (size_t)tid*8);
        }
      };
      auto stW9 = [&](int c0, int k, int buf) {  // 2 uniform instrs
        const unsigned short* Wk = Wb + ((size_t)k * Cout + f0) * Wstr + c0;
#pragma unroll
        for (int j = 0; j < 2; ++j) {
          const int rl = j*64 + r0;
          const int cs = ((cq ^ (rl >> 1)) & 3) << 3;
          gl_lds16(Wk + (size_t)rl*Wstr + cs, Ws + buf*4096 + j*2048 + (size_t)tid*8);
        }
      };
      stA9(0); stW9(0, 0, 0); stW9(0, 1, 1);     // 3+2+2 = 7 in flight
      for (int c0 = 0; c0 < Cin; c0 += 32) {
        const bool last = (c0 + 32 >= Cin);
#pragma unroll
        for (int k = 0; k < 9; ++k) {
          // counted wait: retire everything except the newest W-pair (issued
          // 1 phase ago); the pair we read now was issued 2 phases ago.
          if (k == 8 && last) asm volatile("s_waitcnt vmcnt(0)" ::: "memory");
          else                asm volatile("s_waitcnt vmcnt(2)" ::: "memory");
          __builtin_amdgcn_s_barrier();
          asm volatile("" ::: "memory");
          if (k <= 6)               stW9(c0, k + 2, (k + 2) % 3);
          else if (k == 7 && !last) stW9(c0 + 32, 0, 0);
          const unsigned short* Wsk = Ws + (k % 3)*4096;
          short8 af[4], bfv[4];
#pragma unroll
          for (int mt = 0; mt < 4; mt++) af[mt]  = rdfrag(As, k + wt + mt*16 + lr);
#pragma unroll
          for (int nt = 0; nt < 4; nt++) bfv[nt] = rdfrag(Wsk, wf + nt*16 + lr);
          if (k == 8 && !last) {
            // my As/Ws reads are in regs; fence, then all waves' reads done
            asm volatile("s_waitcnt lgkmcnt(0)" ::: "memory");
            __builtin_amdgcn_s_barrier();
            asm volatile("" ::: "memory");
            stA9(c0 + 32);            // DMA overlaps the 16 MFMAs below
            stW9(c0 + 32, 1, 1);      // next chunk k=1 reads buf 1
          }
#pragma unroll
          for (int mt = 0; mt < 4; mt++)
#pragma unroll
            for (int nt = 0; nt < 4; nt++)
              acc[mt][nt] = __builtin_amdgcn_mfma_f32_16x16x32_bf16(af[mt], bfv[nt], acc[mt][nt], 0, 0, 0);
        }
      }
    }
  }
  // epilogue: D row t = (lane>>4)*4+r, col f = lane&15
#pragma unroll
  for (int mt = 0; mt < 4; mt++) {
    int trow = t0 + wt + mt*16 + lh*4;
#pragma unroll
    for (int nt = 0; nt < 4; nt++) {
      int f = f0 + wf + nt*16 + lr;
      float bb = (!maskmode && bias) ? bias[f] : 0.f;
#pragma unroll
      for (int r = 0; r < 4; r++) {
        float v;
        if (maskmode) {
          v = acc[mt][nt][r] * scale;
          if (f >= slb) v = NEGF;
        } else {
          v = acc[mt][nt][r] + bb;
          if (relu) v = fmaxf(v, 0.f);
        }
        if (O32) O32[(size_t)b*O32bO + (size_t)(trow + r)*O32str + f] = v;
        if (O16) O16[(size_t)b*O16bO + (size_t)h*O16hO + (size_t)(trow + r)*O16str + f] = f2bf(v);
      }
    }
  }
}

// ---------- V transpose: VT[bh][d][t] <- qkv V section; zero t >= sl[b] ------
__global__ __launch_bounds__(256) void vtrans_kernel(const unsigned short* __restrict__ qkv,
    const int* __restrict__ sl, unsigned short* __restrict__ VT) {
  const int z = blockIdx.z, b = z >> 1, h = z & 1;
  const int t0 = blockIdx.x << 5, d0 = blockIdx.y << 5;
  __shared__ unsigned short tile[32][33];
  const int tx = threadIdx.x, ty = threadIdx.y;
  const int slb = sl[b];
  const unsigned short* src = qkv + (size_t)b*TX*768 + 512 + h*DK;
#pragma unroll
  for (int i = 0; i < 4; i++)
    tile[ty + i*8][tx] = src[(size_t)(t0 + ty + i*8)*768 + d0 + tx];
  __syncthreads();
#pragma unroll
  for (int i = 0; i < 4; i++) {
    unsigned short v = (t0 + tx < slb) ? tile[tx][ty + i*8] : (unsigned short)0;
    VT[((size_t)z*DK + d0 + ty + i*8)*512 + t0 + tx] = v;
  }
}

// ---------- softmax over bf16 score rows ----------
__global__ __launch_bounds__(256) void softmax_kernel(unsigned short* __restrict__ S) {
  const int row = blockIdx.x*4 + (threadIdx.x >> 6);
  const int lane = threadIdx.x & 63;
  unsigned short* p = S + (size_t)row*512 + lane*8;
  short8 raw = *(const short8*)p;
  float a[8];
#pragma unroll
  for (int i = 0; i < 8; i++) a[i] = bf2f((unsigned short)raw[i]);
  float m = a[0];
#pragma unroll
  for (int i = 1; i < 8; i++) m = fmaxf(m, a[i]);
  m = wmax(m);
  float s = 0.f;
#pragma unroll
  for (int i = 0; i < 8; i++) { a[i] = __expf(a[i]-m); s += a[i]; }
  s = wsum(s);
  float inv = 1.f / s;
  short8 o;
#pragma unroll
  for (int i = 0; i < 8; i++) o[i] = (short)f2bf(a[i] * inv);
  *(short8*)p = o;
}

// ---------- residual(bf16) + layernorm + pad-mask; rewrites bf16 padded xb ----------
__global__ __launch_bounds__(256) void ln_kernel(const float* __restrict__ tin,
    const float* __restrict__ g, const float* __restrict__ bt, const int* __restrict__ sl,
    unsigned short* __restrict__ xbo /* pre-offset +4 rows */) {
  const int row = blockIdx.x*4 + (threadIdx.x >> 6);
  const int b = row >> 9, t = row & 511;
  const int lane = threadIdx.x & 63;
  unsigned short* xp = xbo + ((size_t)b*TXP + t)*256 + lane*4;
  f32x4 tv = *(const f32x4*)(tin + (size_t)row*256 + lane*4);
  ushort4v rv4 = *(const ushort4v*)xp;
  f32x4 s; float su = 0.f, sq = 0.f;
#pragma unroll
  for (int i = 0; i < 4; i++) {
    s[i] = tv[i] + bf2f(rv4[i]);
    su += s[i]; sq += s[i]*s[i];
  }
  su = wsum(su); sq = wsum(sq);
  float mean = su * (1.f/256.f);
  float var = fmaxf(sq * (1.f/256.f) - mean*mean, 0.f);
  float rs = rsqrtf(var + 1e-5f);
  f32x4 gg = *(const f32x4*)(g + lane*4);
  f32x4 bb = *(const f32x4*)(bt + lane*4);
  bool padr = (t >= sl[b]);
  f32x4 y;
#pragma unroll
  for (int i = 0; i < 4; i++) {
    float yy = (s[i]-mean)*rs*gg[i] + bb[i];
    y[i] = padr ? 0.f : yy;
  }
  store_bf16x4(xp, y);
}

// ---------- MAS: masked transpose of value ----------
__global__ __launch_bounds__(256) void transpose_mask(const float* __restrict__ value,
    const int* __restrict__ sl, const int* __restrict__ ml, float* __restrict__ vT) {
  const int b = blockIdx.z;
  const int x0 = blockIdx.y << 5, y0 = blockIdx.x << 5;
  __shared__ float tile[32][33];
  const int tx = threadIdx.x, ty = threadIdx.y;
  const int slb = sl[b], mlb = ml[b];
#pragma unroll
  for (int i = 0; i < 4; i++) {
    int x = x0 + ty + i*8, y = y0 + tx;
    float v = value[((size_t)b*TX + x)*TY + y];
    tile[ty + i*8][tx] = (x < slb && y < mlb) ? v : 0.f;
  }
  __syncthreads();
#pragma unroll
  for (int i = 0; i < 4; i++) {
    int y = y0 + ty + i*8, x = x0 + tx;
    vT[((size_t)b*TY + y)*TX + x] = tile[tx][ty + i*8];
  }
}

// ---------- fused MAS DP (forward + backward), one wave per batch ----------
template<bool RAMP>
__device__ __forceinline__ void dp_comp8(
    int jb, const float* valbuf, unsigned long long* dll,
    float v[8], int lane, int xbase, unsigned int vmask, unsigned int fmask,
    bool lane0) {
  unsigned int w0 = 0, w1 = 0;
#pragma unroll
  for (int u = 0; u < 8; ++u) {
    const int j = jb*8 + u;
    f32x4 a0 = *(const f32x4*)(valbuf + u*512 + lane*8);
    f32x4 a1 = *(const f32x4*)(valbuf + u*512 + lane*8 + 4);
    float vp = lane_shr1(v[7]);          // old v[7] of lane-1
    if (lane0) vp = NEGF;
    unsigned int ge = 0;
#pragma unroll
    for (int i = 7; i >= 1; --i) {       // descending: v[i-1] still old
      unsigned int g = (v[i] >= v[i-1]) ? 1u : 0u;
      ge = (ge << 1) | g;
      float nv = fmaxf(v[i], v[i-1]) + ((i < 4) ? a0[i] : a1[i-4]);
      if (RAMP) v[i] = (xbase + i <= j) ? nv : NEGF;
      else      v[i] = nv;
    }
    {
      unsigned int g = (v[0] >= vp) ? 1u : 0u;
      ge = (ge << 1) | g;
      float nv = fmaxf(v[0], vp) + a0[0];
      if (RAMP) v[0] = (xbase <= j) ? nv : NEGF;
      else      v[0] = nv;
    }
    unsigned int byt = (ge & vmask) | fmask;   // force-1 where x >= slb
    if (u < 4) w0 |= byt << (8*u); else w1 |= byt << (8*(u-4));
  }
  dll[jb*64 + lane] = ((unsigned long long)w1 << 32) | w0;
}

__global__ __launch_bounds__(64, 1) void dp_fused(const float* __restrict__ vT,
    const int* __restrict__ sl, const int* __restrict__ ml,
    int* __restrict__ idxout) {
  __shared__ float sval[3*4096];              // 3 x (8 j x 512 x) f32 = 48 KB
  __shared__ unsigned long long dll[TY*8];    // direction bitmap, 64 KB
  unsigned char* dld = (unsigned char*)dll;
  const int b = blockIdx.x, lane = threadIdx.x;
  const int slb = sl[b], mlb = ml[b];
  const float* vb = vT + (size_t)b*TY*TX;
  const int xbase = lane*8;
  const bool lane0 = (lane == 0);
  unsigned int vmaskv = 0;
#pragma unroll
  for (int i = 0; i < 8; ++i) if (xbase + i < slb) vmaskv |= (1u << i);
  const unsigned int fmaskv = (~vmaskv) & 0xffu;
  float v[8];
#pragma unroll
  for (int i = 0; i < 8; ++i) v[i] = 0.f;
  const int jbEnd = (mlb + 7) >> 3;           // in [64,128]

  auto stage = [&](int jb, float* buf) {      // 16 async loads, 16B/lane
    const float* src = vb + (size_t)jb*8*TX;
#pragma unroll
    for (int u = 0; u < 8; ++u) {
      gl_lds16f(src + u*TX + lane*4,       buf + u*512);
      gl_lds16f(src + u*TX + 256 + lane*4, buf + u*512 + 256);
    }
  };
  stage(0, sval);
  stage(1, sval + 4096);
  stage(2, sval + 8192);
  int buf = 0;
  int jb = 0;
  for (; jb < 64; ++jb) {
    if (jb + 2 < jbEnd)      asm volatile("s_waitcnt vmcnt(32)" ::: "memory");
    else if (jb + 1 < jbEnd) asm volatile("s_waitcnt vmcnt(16)" ::: "memory");
    else                     asm volatile("s_waitcnt vmcnt(0)"  ::: "memory");
    float* vbuf = sval + buf*4096;
    dp_comp8<true>(jb, vbuf, dll, v, lane, xbase, vmaskv, fmaskv, lane0);
    __builtin_amdgcn_sched_barrier(0);
    if (jb + 3 < jbEnd) stage(jb + 3, vbuf);
    buf = (buf == 2) ? 0 : buf + 1;
  }
  for (; jb < jbEnd; ++jb) {
    if (jb + 2 < jbEnd)      asm volatile("s_waitcnt vmcnt(32)" ::: "memory");
    else if (jb + 1 < jbEnd) asm volatile("s_waitcnt vmcnt(16)" ::: "memory");
    else                     asm volatile("s_waitcnt vmcnt(0)"  ::: "memory");
    float* vbuf = sval + buf*4096;
    dp_comp8<false>(jb, vbuf, dll, v, lane, xbase, vmaskv, fmaskv, lane0);
    __builtin_amdgcn_sched_barrier(0);
    if (jb + 3 < jbEnd) stage(jb + 3, vbuf);
    buf = (buf == 2) ? 0 : buf + 1;
  }
  for (int jj = mlb + lane; jj < TY; jj += 64) idxout[b*TY + jj] = -1;
  if (lane0) {
    int* ob = idxout + b*TY;
    int idx = slb - 1;
    int j = mlb - 1;
    while (j >= 6) {
      int o0 = idx >> 3;
      int o1 = (o0 > 0) ? (o0 - 1) : 0;
      unsigned int bc[7], ba[7];
#pragma unroll
      for (int s = 0; s < 7; ++s) {       // 14 independent ds_read_u8
        int r = j - s;
        int rbase = ((r >> 3) << 9) + (r & 7);
        bc[s] = dld[rbase + o0*8];
        ba[s] = dld[rbase + o1*8];
      }
#pragma unroll
      for (int s = 0; s < 7; ++s) {
        ob[j - s] = idx;
        unsigned int byt = ((idx >> 3) == o0) ? bc[s] : ba[s];
        idx += (int)((byt >> (idx & 7)) & 1u) - 1;
      }
      j -= 7;
    }
    while (j >= 0) {
      ob[j] = idx;
      unsigned int byt = dld[((j >> 3) << 9) + (j & 7) + (idx >> 3)*8];
      idx += (int)((byt >> (idx & 7)) & 1u) - 1;
      --j;
    }
  }
}

// ---------- final gather (bf16 activations -> f32 out) ----------
__global__ __launch_bounds__(256) void gather_kernel(const unsigned short* __restrict__ xbo,
    const int* __restrict__ idxout, float* __restrict__ out) {
  const int row = blockIdx.x*4 + (threadIdx.x >> 6);
  const int lane = threadIdx.x & 63;
  const int b = row >> 10;
  const int idx = idxout[row];
  f32x4 v;
  if (idx >= 0) {
    ushort4v r = *(const ushort4v*)(xbo + ((size_t)b*TXP + idx)*256 + lane*4);
#pragma unroll
    for (int i = 0; i < 4; i++) v[i] = bf2f(r[i]);
  } else { v[0]=0.f; v[1]=0.f; v[2]=0.f; v[3]=0.f; }
  *(f32x4*)(out + (size_t)row*256 + lane*4) = v;
}

// ---------- launch ----------
extern "C" void kernel_launch(void* const* d_in, const int* in_sizes, int n_in,
                              void* d_out, int out_size, void* d_ws, size_t ws_size,
                              hipStream_t stream) {
  const int*   tokens = (const int*)d_in[0];
  const int*   sl     = (const int*)d_in[1];
  const int*   ml     = (const int*)d_in[2];
  const float* value  = (const float*)d_in[3];
  const float* emb    = (const float*)d_in[4];
  const float* pos    = (const float*)d_in[5];
  const float* wq     = (const float*)d_in[6];
  const float* bq     = (const float*)d_in[7];
  const float* wk     = (const float*)d_in[8];
  const float* bk     = (const float*)d_in[9];
  const float* wv     = (const float*)d_in[10];
  const float* bv     = (const float*)d_in[11];
  const float* wo     = (const float*)d_in[12];
  const float* bo     = (const float*)d_in[13];
  const float* ln1g   = (const float*)d_in[14];
  const float* ln1bb  = (const float*)d_in[15];
  const float* c1w    = (const float*)d_in[16];
  const float* c1b    = (const float*)d_in[17];
  const float* c2w    = (const float*)d_in[18];
  const float* c2b    = (const float*)d_in[19];
  const float* ln2g   = (const float*)d_in[20];
  const float* ln2bb  = (const float*)d_in[21];

  char* w8 = (char*)d_ws;
  unsigned short* xb     = (unsigned short*)(w8 + OFF_XB);
  unsigned short* hb     = (unsigned short*)(w8 + OFF_HB);
  unsigned short* qkvb   = (unsigned short*)(w8 + OFF_QKV);
  unsigned short* S      = (unsigned short*)(w8 + OFF_S);
  float*          vT     = (float*)(w8 + OFF_HB);            // MAS-phase alias
  unsigned short* VT     = (unsigned short*)(w8 + OFF_T1);   // attention-phase alias
  unsigned short* ao     = (unsigned short*)(w8 + OFF_AO);
  float*          T1     = (float*)(w8 + OFF_T1);
  unsigned short* wqkv_r = (unsigned short*)(w8 + OFF_WQKV);
  float*          bqkv   = (float*)(w8 + OFF_BQKV);
  unsigned short* wo_r   = (unsigned short*)(w8 + OFF_WO);
  unsigned short* wt1r   = (unsigned short*)(w8 + OFF_WT1);
  unsigned short* wt2r   = (unsigned short*)(w8 + OFF_WT2);
  int*            idxout = (int*)(w8 + OFF_IDX);
  float*          out    = (float*)d_out;

  const float scale = 0.08838834764831843f;  // 1/sqrt(128)

  // weight repack
  repack_qkvw<<<(NL*768*256 + 255)/256, 256, 0, stream>>>(wq, wk, wv, wqkv_r);
  repack_bias<<<(NL*768 + 255)/256, 256, 0, stream>>>(bq, bk, bv, bqkv);
  repack_wo<<<(NL*256*256 + 255)/256, 256, 0, stream>>>(wo, wo_r);
  repack_c1<<<(NL*9*1024*256 + 255)/256, 256, 0, stream>>>(c1w, wt1r);
  repack_c2<<<(NL*9*256*1024 + 255)/256, 256, 0, stream>>>(c2w, wt2r);

  // monotonic alignment search first (vT aliases HB+QKV+part of S!)
  transpose_mask<<<dim3(32, 16, 32), dim3(32, 8), 0, stream>>>(value, sl, ml, vT);
  dp_fused<<<32, 64, 0, stream>>>(vT, sl, ml, idxout);

  // qkvb must be finite everywhere (skip-blocks leave rows >= sl unwritten).
  // MUST be issued AFTER dp_fused: vT covers this region (R2-R4 NaN bug).
  hipMemsetAsync(qkvb, 0, SZ_QKV, stream);

  // halo zero + embedding
  zero_halo<<<(327680 + 255)/256, 256, 0, stream>>>(xb, hb);
  embed_kernel<<<4096, 256, 0, stream>>>(tokens, emb, pos, xb + 4*256);

  // encoder layers
  for (int l = 0; l < NL; l++) {
    // QKV projection: [B] x: 512x256 @ 256x768 -> qkvb bf16
    gemm_mfma<1><<<dim3(4, 6, 32), 256, 0, stream>>>(
        xb + 4*256, (long long)TXP*256, 0, 256,
        wqkv_r + (size_t)l*768*256, 0, 0, 256,
        bqkv + l*768,
        nullptr, 0, 0,
        qkvb, (long long)TX*768, 0, 768,
        256, 768, 0, 1, nullptr, 0.f, 0, sl, 0);
    // scores: per (b,h): Q[512x128] @ K^T -> S bf16, scale + key mask
    gemm_mfma<1><<<dim3(4, 4, 64), 256, 0, stream>>>(
        qkvb, (long long)TX*768, 128, 768,
        qkvb + 256, (long long)TX*768, 128, 768,
        nullptr,
        nullptr, 0, 0,
        S, (long long)2*512*512, (long long)512*512, 512,
        128, 512, 0, 2, sl, scale, 1, sl, 0);
    softmax_kernel<<<8192, 256, 0, stream>>>(S);
    vtrans_kernel<<<dim3(16, 4, 64), dim3(32, 8), 0, stream>>>(qkvb, sl, VT);
    // AV: per (b,h): P[512x512] @ V[512x128] (VT rows are d) -> ao bf16
    gemm_mfma<1><<<dim3(4, 1, 64), 256, 0, stream>>>(
        S, (long long)2*512*512, (long long)512*512, 512,
        VT, (long long)2*DK*512, (long long)DK*512, 512,
        nullptr,
        nullptr, 0, 0,
        ao, (long long)TX*256, 128, 256,
        512, 128, 0, 2, nullptr, 0.f, 0, sl, 0);
    // out-proj -> T1 f32 (after AV: T1/VT alias hand-off)
    gemm_mfma<1><<<dim3(4, 2, 32), 256, 0, stream>>>(
        ao, (long long)TX*256, 0, 256,
        wo_r + (size_t)l*256*256, 0, 0, 256,
        bo + l*256,
        T1, (long long)TX*256, 256,
        nullptr, 0, 0, 0,
        256, 256, 0, 1, nullptr, 0.f, 0, sl, 0);
    ln_kernel<<<4096, 256, 0, stream>>>(T1, ln1g + l*256, ln1bb + l*256, sl, xb + 4*256);
    // conv1 (K=9) -> hb bf16 (relu); outputs needed for rows < sl+4
    gemm_mfma<9><<<dim3(4, 8, 32), 256, 0, stream>>>(
        xb, (long long)TXP*256, 0, 256,
        wt1r + (size_t)l*9*1024*256, 0, 0, 256,
        c1b + l*1024,
        nullptr, 0, 0,
        hb + 4*1024, (long long)TXP*1024, 0, 1024,
        256, 1024, 1, 1, nullptr, 0.f, 0, sl, 4);
    // conv2 (K=9) -> T1 f32
    gemm_mfma<9><<<dim3(4, 2, 32), 256, 0, stream>>>(
        hb, (long long)TXP*1024, 0, 1024,
        wt2r + (size_t)l*9*256*1024, 0, 0, 1024,
        c2b + l*256,
        T1, (long long)TX*256, 256,
        nullptr, 0, 0, 0,
        1024, 256, 0, 1, nullptr, 0.f, 0, sl, 0);
    ln_kernel<<<4096, 256, 0, stream>>>(T1, ln2g + l*256, ln2bb + l*256, sl, xb + 4*256);
  }

  // expand via alignment path
  gather_kernel<<<8192, 256, 0, stream>>>(xb + 4*256, idxout, out);
  (void)in_sizes; (void)n_in; (void)out_size; (void)ws_size;
}